// Round 1
// baseline (1734.957 us; speedup 1.0000x reference)
//
#include <hip/hip_runtime.h>
#include <hip/hip_bf16.h>
#include <stdint.h>

#define N_NODES 100000
#define N_EDGES 3200000
#define F_IN    512
#define HIDDEN  64
#define NCLS    64

#define BROWS   128                 // rows per bucket
#define NBKT    782                 // ceil(N_NODES / BROWS)
#define NBKT_PAD 1024
#define CHUNK   4096                // edges per bucket_scatter block
#define CAP     4608                // fixed slots per bucket (mean 4092 + ~8 sigma)
#define OVF_CAP 8192                // overflow side-list capacity (never hit in practice)
#define SENTINEL ((int)0x80000000)

typedef float v4f __attribute__((ext_vector_type(4)));
typedef short v8s __attribute__((ext_vector_type(8)));

// fp32 -> bf16 bits, round-to-nearest-even
__device__ __forceinline__ unsigned short f2bf(float f){
  unsigned u = __float_as_uint(f);
  u += 0x7fffu + ((u >> 16) & 1u);
  return (unsigned short)(u >> 16);
}
__device__ __forceinline__ float bflo(unsigned u){ return __uint_as_float(u << 16); }

// ---------------------------------------------------------------------------
// Pre-pack W1/W2 into MFMA B-fragment order; also zero the bucket cursors +
// overflow counter (saves a memset dispatch).
// ---------------------------------------------------------------------------
__global__ void prep_weights(const float* __restrict__ W1, const float* __restrict__ W2,
                             unsigned short* __restrict__ w1f, unsigned short* __restrict__ w2f,
                             int* __restrict__ zeroc){
  int t = blockIdx.x * 256 + threadIdx.x;
  if (t < NBKT*16 + 16) zeroc[t] = 0;          // bcur (padded) + ovf_cnt
  if (t < 16*4*64*8){
    int j = t & 7, lane = (t >> 3) & 63, nt = (t >> 9) & 3, ks = t >> 11;
    int m = lane & 15, q = lane >> 4;
    int k = ks*32 + q*8 + j, n = nt*16 + m;
    w1f[t] = f2bf(W1[k*HIDDEN + n]);
  } else {
    int u = t - 16*4*64*8;
    if (u < 2*4*64*8){
      int j = u & 7, lane = (u >> 3) & 63, nt = (u >> 9) & 3, ks = u >> 11;
      int m = lane & 15, q = lane >> 4;
      int k = ks*32 + q*8 + j, n = nt*16 + m;
      w2f[u] = f2bf(W2[k*NCLS + n]);
    }
  }
}

// ---------------------------------------------------------------------------
// Fused MLP: logits(bf16) = relu(X@W1+b1)@W2+b2. One wave = 16 nodes.
// C/D layout: col=lane&15, row=quad*4+reg (measured, m89/m91).
// ---------------------------------------------------------------------------
__global__ __launch_bounds__(256) void mlp_kernel(
    const float* __restrict__ X, const float* __restrict__ b1,
    const float* __restrict__ b2,
    const unsigned short* __restrict__ w1f, const unsigned short* __restrict__ w2f,
    unsigned short* __restrict__ logits){
  __shared__ __align__(16) float lds[4][16][68];
  int tid  = threadIdx.x;
  int wid  = tid >> 6, lane = tid & 63;
  int m    = lane & 15, q = lane >> 4;
  int base = blockIdx.x * 64 + wid * 16;
  if (base > N_NODES - 16) base = N_NODES - 16;   // tail waves redo last tile (benign)

  const float* rp = X + (size_t)(base + m) * F_IN + q * 8;
  const v8s* w1v = (const v8s*)w1f;
  const v8s* w2v = (const v8s*)w2f;

  v4f a0c = {0,0,0,0}, a1c = {0,0,0,0}, a2c = {0,0,0,0}, a3c = {0,0,0,0};
  #pragma unroll
  for (int ks = 0; ks < 16; ++ks){
    const float4* pa = (const float4*)(rp + ks * 32);
    float4 x0 = pa[0], x1 = pa[1];
    v8s af;
    af[0]=(short)f2bf(x0.x); af[1]=(short)f2bf(x0.y); af[2]=(short)f2bf(x0.z); af[3]=(short)f2bf(x0.w);
    af[4]=(short)f2bf(x1.x); af[5]=(short)f2bf(x1.y); af[6]=(short)f2bf(x1.z); af[7]=(short)f2bf(x1.w);
    a0c = __builtin_amdgcn_mfma_f32_16x16x32_bf16(af, w1v[(ks*4+0)*64 + lane], a0c, 0,0,0);
    a1c = __builtin_amdgcn_mfma_f32_16x16x32_bf16(af, w1v[(ks*4+1)*64 + lane], a1c, 0,0,0);
    a2c = __builtin_amdgcn_mfma_f32_16x16x32_bf16(af, w1v[(ks*4+2)*64 + lane], a2c, 0,0,0);
    a3c = __builtin_amdgcn_mfma_f32_16x16x32_bf16(af, w1v[(ks*4+3)*64 + lane], a3c, 0,0,0);
  }

  float b1v0 = b1[m], b1v1 = b1[16+m], b1v2 = b1[32+m], b1v3 = b1[48+m];
  #pragma unroll
  for (int r = 0; r < 4; ++r){
    int row = q*4 + r;
    lds[wid][row][     m] = fmaxf(a0c[r] + b1v0, 0.f);
    lds[wid][row][16 + m] = fmaxf(a1c[r] + b1v1, 0.f);
    lds[wid][row][32 + m] = fmaxf(a2c[r] + b1v2, 0.f);
    lds[wid][row][48 + m] = fmaxf(a3c[r] + b1v3, 0.f);
  }
  __syncthreads();

  v4f c0 = {0,0,0,0}, c1 = {0,0,0,0}, c2 = {0,0,0,0}, c3 = {0,0,0,0};
  #pragma unroll
  for (int k2 = 0; k2 < 2; ++k2){
    const float4* ph = (const float4*)&lds[wid][m][k2*32 + q*8];
    float4 h0 = ph[0], h1 = ph[1];
    v8s af;
    af[0]=(short)f2bf(h0.x); af[1]=(short)f2bf(h0.y); af[2]=(short)f2bf(h0.z); af[3]=(short)f2bf(h0.w);
    af[4]=(short)f2bf(h1.x); af[5]=(short)f2bf(h1.y); af[6]=(short)f2bf(h1.z); af[7]=(short)f2bf(h1.w);
    c0 = __builtin_amdgcn_mfma_f32_16x16x32_bf16(af, w2v[(k2*4+0)*64 + lane], c0, 0,0,0);
    c1 = __builtin_amdgcn_mfma_f32_16x16x32_bf16(af, w2v[(k2*4+1)*64 + lane], c1, 0,0,0);
    c2 = __builtin_amdgcn_mfma_f32_16x16x32_bf16(af, w2v[(k2*4+2)*64 + lane], c2, 0,0,0);
    c3 = __builtin_amdgcn_mfma_f32_16x16x32_bf16(af, w2v[(k2*4+3)*64 + lane], c3, 0,0,0);
  }

  float b2v0 = b2[m], b2v1 = b2[16+m], b2v2 = b2[32+m], b2v3 = b2[48+m];
  unsigned short* lp = logits + (size_t)base * NCLS;
  #pragma unroll
  for (int r = 0; r < 4; ++r){
    int row = q*4 + r;
    lp[row*NCLS +      m] = f2bf(c0[r] + b2v0);
    lp[row*NCLS + 16 + m] = f2bf(c1[r] + b2v1);
    lp[row*NCLS + 32 + m] = f2bf(c2[r] + b2v2);
    lp[row*NCLS + 48 + m] = f2bf(c3[r] + b2v3);
  }
}

// ---------------------------------------------------------------------------
// Single pass scatter: edges -> fixed-capacity bucket regions (b*CAP ...).
// LDS staging keeps global writes quasi-coalesced. Cursors are one-per-64B
// (no atomic line ping-pong). Overflow (8-sigma tail) goes to a side list.
// Payload packs local_row(7b)<<17 | col(17b).
// ---------------------------------------------------------------------------
__global__ __launch_bounds__(256) void bucket_scatter(
    const int* __restrict__ rows, const int* __restrict__ cols,
    const float* __restrict__ vals, int* __restrict__ bcur,
    int* __restrict__ ovf_cnt, int4* __restrict__ ovf,
    int2* __restrict__ ebkt){
  __shared__ int  lcnt[NBKT_PAD];   // counts -> exclusive prefix -> cursor
  __shared__ int  lbase[NBKT_PAD];  // global dest base minus local prefix
  __shared__ int  ssum[256];
  __shared__ int2 stage[CHUNK];     // 32 KB
  __shared__ int  sdst[CHUNK];      // 16 KB
  int t = threadIdx.x;
  int base = blockIdx.x * CHUNK;
  int cnt  = min(CHUNK, N_EDGES - base);

  #pragma unroll
  for (int i = 0; i < 4; ++i) lcnt[t*4 + i] = 0;
  __syncthreads();

  int r[16];
  #pragma unroll
  for (int k = 0; k < 16; ++k){
    int li = t + k*256;
    if (li < cnt){
      r[k] = rows[base + li];
      atomicAdd(&lcnt[r[k] >> 7], 1);
    } else r[k] = -1;
  }
  __syncthreads();

  int v0 = lcnt[t*4], v1 = lcnt[t*4+1], v2 = lcnt[t*4+2], v3 = lcnt[t*4+3];
  int s = v0 + v1 + v2 + v3;
  ssum[t] = s; __syncthreads();
  for (int o = 1; o < 256; o <<= 1){
    int add = (t >= o) ? ssum[t - o] : 0;
    __syncthreads();
    ssum[t] += add;
    __syncthreads();
  }
  int run = ssum[t] - s;
  int e0 = run, e1 = run + v0, e2 = run + v0 + v1, e3 = run + v0 + v1 + v2;
  if (v0){ int g = atomicAdd(&bcur[(t*4+0)*16], v0); lbase[t*4+0] = (t*4+0)*CAP + g - e0; }
  if (v1){ int g = atomicAdd(&bcur[(t*4+1)*16], v1); lbase[t*4+1] = (t*4+1)*CAP + g - e1; }
  if (v2){ int g = atomicAdd(&bcur[(t*4+2)*16], v2); lbase[t*4+2] = (t*4+2)*CAP + g - e2; }
  if (v3){ int g = atomicAdd(&bcur[(t*4+3)*16], v3); lbase[t*4+3] = (t*4+3)*CAP + g - e3; }
  lcnt[t*4+0] = e0; lcnt[t*4+1] = e1; lcnt[t*4+2] = e2; lcnt[t*4+3] = e3;
  __syncthreads();

  #pragma unroll
  for (int k = 0; k < 16; ++k){
    if (r[k] >= 0){
      int li = t + k*256;
      int c  = cols[base + li];
      float v = vals[base + li];
      int b  = r[k] >> 7;
      int pos = atomicAdd(&lcnt[b], 1);
      int dest = lbase[b] + pos;
      if (dest < b*CAP + CAP){
        stage[pos] = make_int2(((r[k] & 127) << 17) | c, __float_as_int(v));
        sdst[pos]  = lbase[b];
      } else {
        sdst[pos] = SENTINEL;
        int o = atomicAdd(ovf_cnt, 1);
        if (o < OVF_CAP) ovf[o] = make_int4(r[k], c, __float_as_int(v), 0);
      }
    }
  }
  __syncthreads();

  for (int j = t; j < cnt; j += 256){
    int d = sdst[j];
    if (d != SENTINEL) ebkt[d + j] = stage[j];
  }
}

// ---------------------------------------------------------------------------
// Fused sort+aggregate: one block per bucket. 128x64 fp32 accumulator in LDS
// (32 KB). Lane = channel -> each edge's 128 B logits-row gather is one
// coalesced wave load; accumulate is one ds_add_f32 per edge (2-way bank
// aliasing = free). Edge decode hoisted to SGPRs via readfirstlane (the whole
// wave handles one edge, so the payload is wave-uniform).
// ---------------------------------------------------------------------------
__global__ __launch_bounds__(256) void bucket_agg(
    const int* __restrict__ bcur, const int2* __restrict__ ebkt,
    const unsigned short* __restrict__ logits, float* __restrict__ out){
  __shared__ float acc[BROWS * 64];   // 32 KB
  int b = blockIdx.x, t = threadIdx.x;
  int w = t >> 6, lane = t & 63;

  float4* accv = (float4*)acc;
  for (int j = t; j < BROWS * 16; j += 256) accv[j] = make_float4(0.f, 0.f, 0.f, 0.f);
  __syncthreads();

  int cnt = bcur[b * 16];
  if (cnt > CAP) cnt = CAP;
  const int2* ep = ebkt + (size_t)b * CAP;

  #define UNR 8
  for (int i0 = w * UNR; i0 < cnt; i0 += 4 * UNR){
    int2 ev[UNR];
    #pragma unroll
    for (int k = 0; k < UNR; ++k)
      ev[k] = (i0 + k < cnt) ? ep[i0 + k] : make_int2(0, 0);
    float pv[UNR]; int srow[UNR];
    #pragma unroll
    for (int k = 0; k < UNR; ++k){
      int x  = __builtin_amdgcn_readfirstlane(ev[k].x);
      int vb = __builtin_amdgcn_readfirstlane(ev[k].y);
      unsigned short u = logits[((size_t)(x & 0x1FFFF) << 6) + lane];
      pv[k]   = __int_as_float(vb) * bflo(u);
      srow[k] = (int)(((unsigned)x >> 17) << 6);
    }
    #pragma unroll
    for (int k = 0; k < UNR; ++k)
      atomicAdd(&acc[srow[k] + lane], pv[k]);
  }
  #undef UNR
  __syncthreads();

  int row0 = b * BROWS;
  for (int j = t; j < BROWS * 16; j += 256){
    int row = j >> 4;
    if (row0 + row < N_NODES)
      ((float4*)(out + ((size_t)(row0 + row) << 6)))[j & 15] = accv[j];
  }
}

// Overflow side-list: applied with global atomics after bucket_agg has
// written out. cnt==0 in practice -> 256 blocks exit immediately.
__global__ __launch_bounds__(256) void ovf_apply(
    const int* __restrict__ ovf_cnt, const int4* __restrict__ ovf,
    const unsigned short* __restrict__ logits, float* __restrict__ out){
  int cnt = ovf_cnt[0];
  if (cnt > OVF_CAP) cnt = OVF_CAP;
  long total = (long)cnt * 64;
  for (long i = (long)blockIdx.x * 256 + threadIdx.x; i < total; i += (long)gridDim.x * 256){
    int e = (int)(i >> 6), c = (int)(i & 63);
    int4 ev = ovf[e];
    float lv = bflo(logits[((size_t)ev.y << 6) + c]);
    atomicAdd(&out[((size_t)ev.x << 6) + c], __int_as_float(ev.z) * lv);
  }
}

// Fallback if workspace is too small: direct atomic scatter.
__global__ void scatter_atomic(const int* __restrict__ rows, const int* __restrict__ cols,
                               const float* __restrict__ vals,
                               const unsigned short* __restrict__ logits,
                               float* __restrict__ out){
  long g = (long)blockIdx.x * 256 + threadIdx.x;
  int e = (int)(g >> 6), c = (int)(g & 63);
  if (e < N_EDGES){
    float lv = __uint_as_float(((unsigned)logits[(size_t)cols[e] * NCLS + c]) << 16);
    atomicAdd(&out[(size_t)rows[e] * NCLS + c], vals[e] * lv);
  }
}

extern "C" void kernel_launch(void* const* d_in, const int* in_sizes, int n_in,
                              void* d_out, int out_size, void* d_ws, size_t ws_size,
                              hipStream_t stream){
  const float* X     = (const float*)d_in[0];
  const int*   erows = (const int*)  d_in[1];
  const int*   ecols = (const int*)  d_in[2];
  const float* evals = (const float*)d_in[3];
  const float* W1    = (const float*)d_in[4];
  const float* b1    = (const float*)d_in[5];
  const float* W2    = (const float*)d_in[6];
  const float* b2    = (const float*)d_in[7];
  float* out = (float*)d_out;

  char* ws = (char*)d_ws;
  size_t off = 0;
  auto alloc = [&](size_t bytes) -> char* {
    char* p = ws + off;
    off = (off + bytes + 255) & ~(size_t)255;
    return p;
  };
  unsigned short* logits = (unsigned short*)alloc((size_t)N_NODES * NCLS * 2); // 12.8 MB
  unsigned short* w1f    = (unsigned short*)alloc(16*4*64*8 * 2);
  unsigned short* w2f    = (unsigned short*)alloc(2*4*64*8 * 2);
  int*  bcur = (int*)alloc((size_t)(NBKT*16 + 16) * 4);   // padded cursors + ovf_cnt
  int*  ovfc = bcur + NBKT*16;
  int4* ovf  = (int4*)alloc((size_t)OVF_CAP * 16);
  int2* ebkt = (int2*)alloc((size_t)NBKT * CAP * 8);      // 28.8 MB fixed-cap regions
  size_t full_need = off;   // ~42 MB

  prep_weights<<<144, 256, 0, stream>>>(W1, W2, w1f, w2f, bcur);
  mlp_kernel<<<(N_NODES + 63) / 64, 256, 0, stream>>>(X, b1, b2, w1f, w2f, logits);

  if (ws_size >= full_need){
    bucket_scatter<<<(N_EDGES + CHUNK - 1) / CHUNK, 256, 0, stream>>>(
        erows, ecols, evals, bcur, ovfc, ovf, ebkt);
    bucket_agg<<<NBKT, 256, 0, stream>>>(bcur, ebkt, logits, out);
    ovf_apply<<<256, 256, 0, stream>>>(ovfc, ovf, logits, out);
  } else {
    hipMemsetAsync(out, 0, (size_t)N_NODES * NCLS * 4, stream);
    scatter_atomic<<<(int)(((long)N_EDGES * 64 + 255) / 256), 256, 0, stream>>>(
        erows, ecols, evals, logits, out);
  }
}

// Round 2
// 1601.068 us; speedup vs baseline: 1.0836x; 1.0836x over previous
//
#include <hip/hip_runtime.h>
#include <hip/hip_bf16.h>
#include <stdint.h>

#define N_NODES 100000
#define N_EDGES 3200000
#define F_IN    512
#define HIDDEN  64
#define NCLS    64

#define BROWS   64                  // rows per bucket
#define NBKT    1563                // ceil(N_NODES / BROWS)
#define NBKT_PAD 1792               // scan padding (7 per thread * 256)
#define CHUNK   4096                // edges per bucket_scatter block
#define CAP     2432                // fixed slots per bucket (mean 2046 + ~8.5 sigma)
#define OVF_CAP 8192                // overflow side-list capacity (never hit in practice)
#define SENTINEL ((int)0x80000000)

typedef float v4f __attribute__((ext_vector_type(4)));
typedef short v8s __attribute__((ext_vector_type(8)));

// fp32 -> bf16 bits, round-to-nearest-even
__device__ __forceinline__ unsigned short f2bf(float f){
  unsigned u = __float_as_uint(f);
  u += 0x7fffu + ((u >> 16) & 1u);
  return (unsigned short)(u >> 16);
}
__device__ __forceinline__ float bflo(unsigned u){ return __uint_as_float(u << 16); }
__device__ __forceinline__ float bfhi(unsigned u){ return __uint_as_float(u & 0xffff0000u); }

// ---------------------------------------------------------------------------
// Pre-pack W1/W2 into MFMA B-fragment order; also zero the bucket cursors +
// overflow counter (saves a memset dispatch).
// ---------------------------------------------------------------------------
__global__ void prep_weights(const float* __restrict__ W1, const float* __restrict__ W2,
                             unsigned short* __restrict__ w1f, unsigned short* __restrict__ w2f,
                             int* __restrict__ zeroc){
  int t = blockIdx.x * 256 + threadIdx.x;
  if (t < NBKT*16 + 16) zeroc[t] = 0;          // bcur (padded) + ovf_cnt
  if (t < 16*4*64*8){
    int j = t & 7, lane = (t >> 3) & 63, nt = (t >> 9) & 3, ks = t >> 11;
    int m = lane & 15, q = lane >> 4;
    int k = ks*32 + q*8 + j, n = nt*16 + m;
    w1f[t] = f2bf(W1[k*HIDDEN + n]);
  } else {
    int u = t - 16*4*64*8;
    if (u < 2*4*64*8){
      int j = u & 7, lane = (u >> 3) & 63, nt = (u >> 9) & 3, ks = u >> 11;
      int m = lane & 15, q = lane >> 4;
      int k = ks*32 + q*8 + j, n = nt*16 + m;
      w2f[u] = f2bf(W2[k*NCLS + n]);
    }
  }
}

// ---------------------------------------------------------------------------
// Fused MLP: logits(bf16) = relu(X@W1+b1)@W2+b2. One wave = 16 nodes.
// C/D layout: col=lane&15, row=quad*4+reg (measured, m89/m91).
// ---------------------------------------------------------------------------
__global__ __launch_bounds__(256) void mlp_kernel(
    const float* __restrict__ X, const float* __restrict__ b1,
    const float* __restrict__ b2,
    const unsigned short* __restrict__ w1f, const unsigned short* __restrict__ w2f,
    unsigned short* __restrict__ logits){
  __shared__ __align__(16) float lds[4][16][68];
  int tid  = threadIdx.x;
  int wid  = tid >> 6, lane = tid & 63;
  int m    = lane & 15, q = lane >> 4;
  int base = blockIdx.x * 64 + wid * 16;
  if (base > N_NODES - 16) base = N_NODES - 16;   // tail waves redo last tile (benign)

  const float* rp = X + (size_t)(base + m) * F_IN + q * 8;
  const v8s* w1v = (const v8s*)w1f;
  const v8s* w2v = (const v8s*)w2f;

  v4f a0c = {0,0,0,0}, a1c = {0,0,0,0}, a2c = {0,0,0,0}, a3c = {0,0,0,0};
  #pragma unroll
  for (int ks = 0; ks < 16; ++ks){
    const float4* pa = (const float4*)(rp + ks * 32);
    float4 x0 = pa[0], x1 = pa[1];
    v8s af;
    af[0]=(short)f2bf(x0.x); af[1]=(short)f2bf(x0.y); af[2]=(short)f2bf(x0.z); af[3]=(short)f2bf(x0.w);
    af[4]=(short)f2bf(x1.x); af[5]=(short)f2bf(x1.y); af[6]=(short)f2bf(x1.z); af[7]=(short)f2bf(x1.w);
    a0c = __builtin_amdgcn_mfma_f32_16x16x32_bf16(af, w1v[(ks*4+0)*64 + lane], a0c, 0,0,0);
    a1c = __builtin_amdgcn_mfma_f32_16x16x32_bf16(af, w1v[(ks*4+1)*64 + lane], a1c, 0,0,0);
    a2c = __builtin_amdgcn_mfma_f32_16x16x32_bf16(af, w1v[(ks*4+2)*64 + lane], a2c, 0,0,0);
    a3c = __builtin_amdgcn_mfma_f32_16x16x32_bf16(af, w1v[(ks*4+3)*64 + lane], a3c, 0,0,0);
  }

  float b1v0 = b1[m], b1v1 = b1[16+m], b1v2 = b1[32+m], b1v3 = b1[48+m];
  #pragma unroll
  for (int r = 0; r < 4; ++r){
    int row = q*4 + r;
    lds[wid][row][     m] = fmaxf(a0c[r] + b1v0, 0.f);
    lds[wid][row][16 + m] = fmaxf(a1c[r] + b1v1, 0.f);
    lds[wid][row][32 + m] = fmaxf(a2c[r] + b1v2, 0.f);
    lds[wid][row][48 + m] = fmaxf(a3c[r] + b1v3, 0.f);
  }
  __syncthreads();

  v4f c0 = {0,0,0,0}, c1 = {0,0,0,0}, c2 = {0,0,0,0}, c3 = {0,0,0,0};
  #pragma unroll
  for (int k2 = 0; k2 < 2; ++k2){
    const float4* ph = (const float4*)&lds[wid][m][k2*32 + q*8];
    float4 h0 = ph[0], h1 = ph[1];
    v8s af;
    af[0]=(short)f2bf(h0.x); af[1]=(short)f2bf(h0.y); af[2]=(short)f2bf(h0.z); af[3]=(short)f2bf(h0.w);
    af[4]=(short)f2bf(h1.x); af[5]=(short)f2bf(h1.y); af[6]=(short)f2bf(h1.z); af[7]=(short)f2bf(h1.w);
    c0 = __builtin_amdgcn_mfma_f32_16x16x32_bf16(af, w2v[(k2*4+0)*64 + lane], c0, 0,0,0);
    c1 = __builtin_amdgcn_mfma_f32_16x16x32_bf16(af, w2v[(k2*4+1)*64 + lane], c1, 0,0,0);
    c2 = __builtin_amdgcn_mfma_f32_16x16x32_bf16(af, w2v[(k2*4+2)*64 + lane], c2, 0,0,0);
    c3 = __builtin_amdgcn_mfma_f32_16x16x32_bf16(af, w2v[(k2*4+3)*64 + lane], c3, 0,0,0);
  }

  float b2v0 = b2[m], b2v1 = b2[16+m], b2v2 = b2[32+m], b2v3 = b2[48+m];
  unsigned short* lp = logits + (size_t)base * NCLS;
  #pragma unroll
  for (int r = 0; r < 4; ++r){
    int row = q*4 + r;
    lp[row*NCLS +      m] = f2bf(c0[r] + b2v0);
    lp[row*NCLS + 16 + m] = f2bf(c1[r] + b2v1);
    lp[row*NCLS + 32 + m] = f2bf(c2[r] + b2v2);
    lp[row*NCLS + 48 + m] = f2bf(c3[r] + b2v3);
  }
}

// ---------------------------------------------------------------------------
// Single pass scatter: edges -> fixed-capacity bucket regions (b*CAP ...).
// LDS staging keeps global writes quasi-coalesced. Cursors are one-per-64B
// (no atomic line ping-pong). Overflow (8-sigma tail) goes to a side list.
// Payload packs local_row(6b)<<17 | col(17b).
// ---------------------------------------------------------------------------
__global__ __launch_bounds__(256) void bucket_scatter(
    const int* __restrict__ rows, const int* __restrict__ cols,
    const float* __restrict__ vals, int* __restrict__ bcur,
    int* __restrict__ ovf_cnt, int4* __restrict__ ovf,
    int2* __restrict__ ebkt){
  __shared__ int  lcnt[NBKT_PAD];   // counts -> exclusive prefix -> cursor
  __shared__ int  lbase[NBKT_PAD];  // global dest base minus local prefix
  __shared__ int  ssum[256];
  __shared__ int2 stage[CHUNK];     // 32 KB
  __shared__ int  sdst[CHUNK];      // 16 KB
  int t = threadIdx.x;
  int base = blockIdx.x * CHUNK;
  int cnt  = min(CHUNK, N_EDGES - base);

  #pragma unroll
  for (int i = 0; i < 7; ++i) lcnt[t*7 + i] = 0;
  __syncthreads();

  int r[16];
  #pragma unroll
  for (int k = 0; k < 16; ++k){
    int li = t + k*256;
    if (li < cnt){
      r[k] = rows[base + li];
      atomicAdd(&lcnt[r[k] >> 6], 1);
    } else r[k] = -1;
  }
  __syncthreads();

  int v[7]; int s = 0;
  #pragma unroll
  for (int k = 0; k < 7; ++k){ v[k] = lcnt[t*7 + k]; s += v[k]; }
  ssum[t] = s; __syncthreads();
  for (int o = 1; o < 256; o <<= 1){
    int add = (t >= o) ? ssum[t - o] : 0;
    __syncthreads();
    ssum[t] += add;
    __syncthreads();
  }
  int run = ssum[t] - s;
  #pragma unroll
  for (int k = 0; k < 7; ++k){
    int b = t*7 + k;
    if (b < NBKT){
      if (v[k]){
        int g = atomicAdd(&bcur[b*16], v[k]);
        lbase[b] = b*CAP + g - run;        // dest = lbase[b] + local_pos
      }
      lcnt[b] = run;                       // local cursor (exclusive prefix)
    }
    run += v[k];
  }
  __syncthreads();

  #pragma unroll
  for (int k = 0; k < 16; ++k){
    if (r[k] >= 0){
      int li = t + k*256;
      int c  = cols[base + li];
      float vv = vals[base + li];
      int b  = r[k] >> 6;
      int pos = atomicAdd(&lcnt[b], 1);
      int dest = lbase[b] + pos;
      if (dest < b*CAP + CAP){
        stage[pos] = make_int2(((r[k] & 63) << 17) | c, __float_as_int(vv));
        sdst[pos]  = lbase[b];
      } else {
        sdst[pos] = SENTINEL;
        int o = atomicAdd(ovf_cnt, 1);
        if (o < OVF_CAP) ovf[o] = make_int4(r[k], c, __float_as_int(vv), 0);
      }
    }
  }
  __syncthreads();

  for (int j = t; j < cnt; j += 256){
    int d = sdst[j];
    if (d != SENTINEL) ebkt[d + j] = stage[j];
  }
}

// ---------------------------------------------------------------------------
// Aggregate: one block per 64-row bucket, 64x68 fp32 LDS accumulator (17.4 KB
// -> up to 8 blocks/CU). Quarter-wave per edge: lane h = uint2 index within
// the logits row, sel = which of 4 edges. Each gather instruction fetches
// 4 x 128 B coalesced; the 4 edge-payload loads of an iteration share one
// 128 B line. 16 edges in flight per wave, no readfirstlane serialization.
// LDS accumulate: 4 ds-atomic f32 per lane per edge; within a quarter-wave
// the 16 lanes hit banks 2-way (free, m136); stride 68 randomizes groups.
// ---------------------------------------------------------------------------
__global__ __launch_bounds__(256) void bucket_agg(
    const int* __restrict__ bcur, const int2* __restrict__ ebkt,
    const unsigned short* __restrict__ logits, float* __restrict__ out){
  __shared__ __align__(16) float acc[BROWS * 68];   // 17408 B
  int b = blockIdx.x, t = threadIdx.x;
  int w = t >> 6, lane = t & 63;
  int h = lane & 15, sel = lane >> 4;

  for (int j = t; j < BROWS * 68; j += 256) acc[j] = 0.f;
  __syncthreads();

  int cnt = bcur[b * 16];
  if (cnt > CAP) cnt = CAP;
  const int2* ep = ebkt + (size_t)b * CAP;
  const uint2* lg = (const uint2*)logits;   // 16 uint2 per node row

  int i = w * 16;
  for (; i + 16 <= cnt; i += 64){
    int2 e0 = ep[i      + sel];
    int2 e1 = ep[i + 4  + sel];
    int2 e2 = ep[i + 8  + sel];
    int2 e3 = ep[i + 12 + sel];
    uint2 u0 = lg[((size_t)(e0.x & 0x1FFFF) << 4) + h];
    uint2 u1 = lg[((size_t)(e1.x & 0x1FFFF) << 4) + h];
    uint2 u2 = lg[((size_t)(e2.x & 0x1FFFF) << 4) + h];
    uint2 u3 = lg[((size_t)(e3.x & 0x1FFFF) << 4) + h];
    float v0 = __int_as_float(e0.y), v1 = __int_as_float(e1.y);
    float v2 = __int_as_float(e2.y), v3 = __int_as_float(e3.y);
    int r0 = (int)(((unsigned)e0.x >> 17) * 68u) + 4*h;
    int r1 = (int)(((unsigned)e1.x >> 17) * 68u) + 4*h;
    int r2 = (int)(((unsigned)e2.x >> 17) * 68u) + 4*h;
    int r3 = (int)(((unsigned)e3.x >> 17) * 68u) + 4*h;
    atomicAdd(&acc[r0+0], v0*bflo(u0.x)); atomicAdd(&acc[r0+1], v0*bfhi(u0.x));
    atomicAdd(&acc[r0+2], v0*bflo(u0.y)); atomicAdd(&acc[r0+3], v0*bfhi(u0.y));
    atomicAdd(&acc[r1+0], v1*bflo(u1.x)); atomicAdd(&acc[r1+1], v1*bfhi(u1.x));
    atomicAdd(&acc[r1+2], v1*bflo(u1.y)); atomicAdd(&acc[r1+3], v1*bfhi(u1.y));
    atomicAdd(&acc[r2+0], v2*bflo(u2.x)); atomicAdd(&acc[r2+1], v2*bfhi(u2.x));
    atomicAdd(&acc[r2+2], v2*bflo(u2.y)); atomicAdd(&acc[r2+3], v2*bfhi(u2.y));
    atomicAdd(&acc[r3+0], v3*bflo(u3.x)); atomicAdd(&acc[r3+1], v3*bfhi(u3.x));
    atomicAdd(&acc[r3+2], v3*bflo(u3.y)); atomicAdd(&acc[r3+3], v3*bfhi(u3.y));
  }
  if (i < cnt){                       // masked tail for this wave's partial chunk
    #pragma unroll
    for (int kk = 0; kk < 16; kk += 4){
      int idx = i + kk + sel;
      int2 ev = (idx < cnt) ? ep[idx] : make_int2(0, 0);
      float vv = (idx < cnt) ? __int_as_float(ev.y) : 0.f;
      uint2 u = lg[((size_t)(ev.x & 0x1FFFF) << 4) + h];
      int rr = (int)(((unsigned)ev.x >> 17) * 68u) + 4*h;
      atomicAdd(&acc[rr+0], vv*bflo(u.x)); atomicAdd(&acc[rr+1], vv*bfhi(u.x));
      atomicAdd(&acc[rr+2], vv*bflo(u.y)); atomicAdd(&acc[rr+3], vv*bfhi(u.y));
    }
  }
  __syncthreads();

  int row0 = b * BROWS;
  for (int j = t; j < BROWS * 16; j += 256){
    int row = j >> 4, q = j & 15;
    if (row0 + row < N_NODES)
      ((float4*)(out + ((size_t)(row0 + row) << 6)))[q] = *(const float4*)&acc[row*68 + q*4];
  }
}

// Overflow side-list: applied with global atomics after bucket_agg has
// written out. cnt==0 in practice -> 256 blocks exit immediately.
__global__ __launch_bounds__(256) void ovf_apply(
    const int* __restrict__ ovf_cnt, const int4* __restrict__ ovf,
    const unsigned short* __restrict__ logits, float* __restrict__ out){
  int cnt = ovf_cnt[0];
  if (cnt > OVF_CAP) cnt = OVF_CAP;
  long total = (long)cnt * 64;
  for (long i = (long)blockIdx.x * 256 + threadIdx.x; i < total; i += (long)gridDim.x * 256){
    int e = (int)(i >> 6), c = (int)(i & 63);
    int4 ev = ovf[e];
    float lv = bflo(logits[((size_t)ev.y << 6) + c]);
    atomicAdd(&out[((size_t)ev.x << 6) + c], __int_as_float(ev.z) * lv);
  }
}

// Fallback if workspace is too small: direct atomic scatter.
__global__ void scatter_atomic(const int* __restrict__ rows, const int* __restrict__ cols,
                               const float* __restrict__ vals,
                               const unsigned short* __restrict__ logits,
                               float* __restrict__ out){
  long g = (long)blockIdx.x * 256 + threadIdx.x;
  int e = (int)(g >> 6), c = (int)(g & 63);
  if (e < N_EDGES){
    float lv = __uint_as_float(((unsigned)logits[(size_t)cols[e] * NCLS + c]) << 16);
    atomicAdd(&out[(size_t)rows[e] * NCLS + c], vals[e] * lv);
  }
}

extern "C" void kernel_launch(void* const* d_in, const int* in_sizes, int n_in,
                              void* d_out, int out_size, void* d_ws, size_t ws_size,
                              hipStream_t stream){
  const float* X     = (const float*)d_in[0];
  const int*   erows = (const int*)  d_in[1];
  const int*   ecols = (const int*)  d_in[2];
  const float* evals = (const float*)d_in[3];
  const float* W1    = (const float*)d_in[4];
  const float* b1    = (const float*)d_in[5];
  const float* W2    = (const float*)d_in[6];
  const float* b2    = (const float*)d_in[7];
  float* out = (float*)d_out;

  char* ws = (char*)d_ws;
  size_t off = 0;
  auto alloc = [&](size_t bytes) -> char* {
    char* p = ws + off;
    off = (off + bytes + 255) & ~(size_t)255;
    return p;
  };
  unsigned short* logits = (unsigned short*)alloc((size_t)N_NODES * NCLS * 2); // 12.8 MB
  unsigned short* w1f    = (unsigned short*)alloc(16*4*64*8 * 2);
  unsigned short* w2f    = (unsigned short*)alloc(2*4*64*8 * 2);
  int*  bcur = (int*)alloc((size_t)(NBKT*16 + 16) * 4);   // padded cursors + ovf_cnt
  int*  ovfc = bcur + NBKT*16;
  int4* ovf  = (int4*)alloc((size_t)OVF_CAP * 16);
  int2* ebkt = (int2*)alloc((size_t)NBKT * CAP * 8);      // 30.4 MB fixed-cap regions
  size_t full_need = off;   // ~44 MB

  prep_weights<<<144, 256, 0, stream>>>(W1, W2, w1f, w2f, bcur);
  mlp_kernel<<<(N_NODES + 63) / 64, 256, 0, stream>>>(X, b1, b2, w1f, w2f, logits);

  if (ws_size >= full_need){
    bucket_scatter<<<(N_EDGES + CHUNK - 1) / CHUNK, 256, 0, stream>>>(
        erows, ecols, evals, bcur, ovfc, ovf, ebkt);
    bucket_agg<<<NBKT, 256, 0, stream>>>(bcur, ebkt, logits, out);
    ovf_apply<<<256, 256, 0, stream>>>(ovfc, ovf, logits, out);
  } else {
    hipMemsetAsync(out, 0, (size_t)N_NODES * NCLS * 4, stream);
    scatter_atomic<<<(int)(((long)N_EDGES * 64 + 255) / 256), 256, 0, stream>>>(
        erows, ecols, evals, logits, out);
  }
}

// Round 3
// 480.594 us; speedup vs baseline: 3.6100x; 3.3314x over previous
//
#include <hip/hip_runtime.h>
#include <hip/hip_bf16.h>
#include <stdint.h>

#define N_NODES 100000
#define N_EDGES 3200000
#define F_IN    512
#define HIDDEN  64
#define NCLS    64

#define BROWS   64                  // rows per bucket
#define NBKT    1563                // ceil(N_NODES / BROWS)
#define NBKT_PAD 1792               // scan padding (7 per thread * 256)
#define CHUNK   4096                // edges per bucket_scatter block
#define CAP     2432                // fixed slots per bucket (mean 2046 + ~8.5 sigma)
#define OVF_CAP 8192                // overflow side-list capacity (never hit in practice)
#define SENTINEL ((int)0x80000000)

typedef float v4f __attribute__((ext_vector_type(4)));
typedef short v8s __attribute__((ext_vector_type(8)));

// fp32 -> bf16 bits, round-to-nearest-even
__device__ __forceinline__ unsigned short f2bf(float f){
  unsigned u = __float_as_uint(f);
  u += 0x7fffu + ((u >> 16) & 1u);
  return (unsigned short)(u >> 16);
}
__device__ __forceinline__ float bflo(unsigned u){ return __uint_as_float(u << 16); }
__device__ __forceinline__ float bfhi(unsigned u){ return __uint_as_float(u & 0xffff0000u); }

// ---------------------------------------------------------------------------
// Pre-pack W1/W2 into MFMA B-fragment order; also zero the bucket cursors +
// overflow counter (saves a memset dispatch).
// ---------------------------------------------------------------------------
__global__ void prep_weights(const float* __restrict__ W1, const float* __restrict__ W2,
                             unsigned short* __restrict__ w1f, unsigned short* __restrict__ w2f,
                             int* __restrict__ zeroc){
  int t = blockIdx.x * 256 + threadIdx.x;
  if (t < NBKT*16 + 16) zeroc[t] = 0;          // bcur (padded) + ovf_cnt
  if (t < 16*4*64*8){
    int j = t & 7, lane = (t >> 3) & 63, nt = (t >> 9) & 3, ks = t >> 11;
    int m = lane & 15, q = lane >> 4;
    int k = ks*32 + q*8 + j, n = nt*16 + m;
    w1f[t] = f2bf(W1[k*HIDDEN + n]);
  } else {
    int u = t - 16*4*64*8;
    if (u < 2*4*64*8){
      int j = u & 7, lane = (u >> 3) & 63, nt = (u >> 9) & 3, ks = u >> 11;
      int m = lane & 15, q = lane >> 4;
      int k = ks*32 + q*8 + j, n = nt*16 + m;
      w2f[u] = f2bf(W2[k*NCLS + n]);
    }
  }
}

// ---------------------------------------------------------------------------
// Fused MLP: logits(bf16) = relu(X@W1+b1)@W2+b2. One wave = 16 nodes.
// C/D layout: col=lane&15, row=quad*4+reg (measured, m89/m91).
// ---------------------------------------------------------------------------
__global__ __launch_bounds__(256) void mlp_kernel(
    const float* __restrict__ X, const float* __restrict__ b1,
    const float* __restrict__ b2,
    const unsigned short* __restrict__ w1f, const unsigned short* __restrict__ w2f,
    unsigned short* __restrict__ logits){
  __shared__ __align__(16) float lds[4][16][68];
  int tid  = threadIdx.x;
  int wid  = tid >> 6, lane = tid & 63;
  int m    = lane & 15, q = lane >> 4;
  int base = blockIdx.x * 64 + wid * 16;
  if (base > N_NODES - 16) base = N_NODES - 16;   // tail waves redo last tile (benign)

  const float* rp = X + (size_t)(base + m) * F_IN + q * 8;
  const v8s* w1v = (const v8s*)w1f;
  const v8s* w2v = (const v8s*)w2f;

  v4f a0c = {0,0,0,0}, a1c = {0,0,0,0}, a2c = {0,0,0,0}, a3c = {0,0,0,0};
  #pragma unroll
  for (int ks = 0; ks < 16; ++ks){
    const float4* pa = (const float4*)(rp + ks * 32);
    float4 x0 = pa[0], x1 = pa[1];
    v8s af;
    af[0]=(short)f2bf(x0.x); af[1]=(short)f2bf(x0.y); af[2]=(short)f2bf(x0.z); af[3]=(short)f2bf(x0.w);
    af[4]=(short)f2bf(x1.x); af[5]=(short)f2bf(x1.y); af[6]=(short)f2bf(x1.z); af[7]=(short)f2bf(x1.w);
    a0c = __builtin_amdgcn_mfma_f32_16x16x32_bf16(af, w1v[(ks*4+0)*64 + lane], a0c, 0,0,0);
    a1c = __builtin_amdgcn_mfma_f32_16x16x32_bf16(af, w1v[(ks*4+1)*64 + lane], a1c, 0,0,0);
    a2c = __builtin_amdgcn_mfma_f32_16x16x32_bf16(af, w1v[(ks*4+2)*64 + lane], a2c, 0,0,0);
    a3c = __builtin_amdgcn_mfma_f32_16x16x32_bf16(af, w1v[(ks*4+3)*64 + lane], a3c, 0,0,0);
  }

  float b1v0 = b1[m], b1v1 = b1[16+m], b1v2 = b1[32+m], b1v3 = b1[48+m];
  #pragma unroll
  for (int r = 0; r < 4; ++r){
    int row = q*4 + r;
    lds[wid][row][     m] = fmaxf(a0c[r] + b1v0, 0.f);
    lds[wid][row][16 + m] = fmaxf(a1c[r] + b1v1, 0.f);
    lds[wid][row][32 + m] = fmaxf(a2c[r] + b1v2, 0.f);
    lds[wid][row][48 + m] = fmaxf(a3c[r] + b1v3, 0.f);
  }
  __syncthreads();

  v4f c0 = {0,0,0,0}, c1 = {0,0,0,0}, c2 = {0,0,0,0}, c3 = {0,0,0,0};
  #pragma unroll
  for (int k2 = 0; k2 < 2; ++k2){
    const float4* ph = (const float4*)&lds[wid][m][k2*32 + q*8];
    float4 h0 = ph[0], h1 = ph[1];
    v8s af;
    af[0]=(short)f2bf(h0.x); af[1]=(short)f2bf(h0.y); af[2]=(short)f2bf(h0.z); af[3]=(short)f2bf(h0.w);
    af[4]=(short)f2bf(h1.x); af[5]=(short)f2bf(h1.y); af[6]=(short)f2bf(h1.z); af[7]=(short)f2bf(h1.w);
    c0 = __builtin_amdgcn_mfma_f32_16x16x32_bf16(af, w2v[(k2*4+0)*64 + lane], c0, 0,0,0);
    c1 = __builtin_amdgcn_mfma_f32_16x16x32_bf16(af, w2v[(k2*4+1)*64 + lane], c1, 0,0,0);
    c2 = __builtin_amdgcn_mfma_f32_16x16x32_bf16(af, w2v[(k2*4+2)*64 + lane], c2, 0,0,0);
    c3 = __builtin_amdgcn_mfma_f32_16x16x32_bf16(af, w2v[(k2*4+3)*64 + lane], c3, 0,0,0);
  }

  float b2v0 = b2[m], b2v1 = b2[16+m], b2v2 = b2[32+m], b2v3 = b2[48+m];
  unsigned short* lp = logits + (size_t)base * NCLS;
  #pragma unroll
  for (int r = 0; r < 4; ++r){
    int row = q*4 + r;
    lp[row*NCLS +      m] = f2bf(c0[r] + b2v0);
    lp[row*NCLS + 16 + m] = f2bf(c1[r] + b2v1);
    lp[row*NCLS + 32 + m] = f2bf(c2[r] + b2v2);
    lp[row*NCLS + 48 + m] = f2bf(c3[r] + b2v3);
  }
}

// ---------------------------------------------------------------------------
// Single pass scatter: edges -> fixed-capacity bucket regions (b*CAP ...).
// LDS staging keeps global writes quasi-coalesced. Cursors are one-per-64B
// (no atomic line ping-pong). Overflow (8-sigma tail) goes to a side list.
// Payload packs local_row(6b)<<17 | col(17b).
// ---------------------------------------------------------------------------
__global__ __launch_bounds__(256) void bucket_scatter(
    const int* __restrict__ rows, const int* __restrict__ cols,
    const float* __restrict__ vals, int* __restrict__ bcur,
    int* __restrict__ ovf_cnt, int4* __restrict__ ovf,
    int2* __restrict__ ebkt){
  __shared__ int  lcnt[NBKT_PAD];   // counts -> exclusive prefix -> cursor
  __shared__ int  lbase[NBKT_PAD];  // global dest base minus local prefix
  __shared__ int  ssum[256];
  __shared__ int2 stage[CHUNK];     // 32 KB
  __shared__ int  sdst[CHUNK];      // 16 KB
  int t = threadIdx.x;
  int base = blockIdx.x * CHUNK;
  int cnt  = min(CHUNK, N_EDGES - base);

  #pragma unroll
  for (int i = 0; i < 7; ++i) lcnt[t*7 + i] = 0;
  __syncthreads();

  int r[16];
  #pragma unroll
  for (int k = 0; k < 16; ++k){
    int li = t + k*256;
    if (li < cnt){
      r[k] = rows[base + li];
      atomicAdd(&lcnt[r[k] >> 6], 1);
    } else r[k] = -1;
  }
  __syncthreads();

  int v[7]; int s = 0;
  #pragma unroll
  for (int k = 0; k < 7; ++k){ v[k] = lcnt[t*7 + k]; s += v[k]; }
  ssum[t] = s; __syncthreads();
  for (int o = 1; o < 256; o <<= 1){
    int add = (t >= o) ? ssum[t - o] : 0;
    __syncthreads();
    ssum[t] += add;
    __syncthreads();
  }
  int run = ssum[t] - s;
  #pragma unroll
  for (int k = 0; k < 7; ++k){
    int b = t*7 + k;
    if (b < NBKT){
      if (v[k]){
        int g = atomicAdd(&bcur[b*16], v[k]);
        lbase[b] = b*CAP + g - run;        // dest = lbase[b] + local_pos
      }
      lcnt[b] = run;                       // local cursor (exclusive prefix)
    }
    run += v[k];
  }
  __syncthreads();

  #pragma unroll
  for (int k = 0; k < 16; ++k){
    if (r[k] >= 0){
      int li = t + k*256;
      int c  = cols[base + li];
      float vv = vals[base + li];
      int b  = r[k] >> 6;
      int pos = atomicAdd(&lcnt[b], 1);
      int dest = lbase[b] + pos;
      if (dest < b*CAP + CAP){
        stage[pos] = make_int2(((r[k] & 63) << 17) | c, __float_as_int(vv));
        sdst[pos]  = lbase[b];
      } else {
        sdst[pos] = SENTINEL;
        int o = atomicAdd(ovf_cnt, 1);
        if (o < OVF_CAP) ovf[o] = make_int4(r[k], c, __float_as_int(vv), 0);
      }
    }
  }
  __syncthreads();

  for (int j = t; j < cnt; j += 256){
    int d = sdst[j];
    if (d != SENTINEL) ebkt[d + j] = stage[j];
  }
}

// ---------------------------------------------------------------------------
// Fused counting-sort + aggregate: one block per 64-row bucket.
// No FP LDS atomics anywhere (hipcc lowers shared-float atomicAdd to a CAS
// retry loop without -munsafe-fp-atomics -> the 1188us wall seen in r1/r2).
// 1) count rows (native int ds_add), 2) 64-lane shuffle scan, 3) scatter
// edges into a sorted LDS array (19.4 KB), 4) round-0's proven register-
// accumulate: quarter-wave per edge, 16 coalesced 128B gathers in flight,
// shfl_xor reduce, float4 store. LDS ~20.5 KB -> 7 blocks/CU capacity.
// ---------------------------------------------------------------------------
__global__ __launch_bounds__(256) void bucket_agg(
    const int* __restrict__ bcur, const int2* __restrict__ ebkt,
    const unsigned short* __restrict__ logits, float* __restrict__ out){
  __shared__ int2 sorted[CAP];        // 19456 B
  __shared__ int  rc[BROWS];
  __shared__ int  rbase[BROWS + 1];
  __shared__ int  rcur[BROWS];
  int b = blockIdx.x, t = threadIdx.x;
  int w = t >> 6, lane = t & 63;
  int h = lane & 15, sel = lane >> 4;

  if (t < BROWS) rc[t] = 0;
  __syncthreads();

  int cnt = bcur[b * 16];
  if (cnt > CAP) cnt = CAP;
  const int2* ep = ebkt + (size_t)b * CAP;

  // pass 1: per-row counts (int atomics = native ds_add_u32)
  for (int j = t; j < cnt; j += 256){
    int x = ((const int*)ep)[2*j];
    atomicAdd(&rc[((unsigned)x) >> 17], 1);
  }
  __syncthreads();

  // 64-lane inclusive shuffle scan (wave 0 only) -> bases + cursors
  if (t < BROWS){
    int c = rc[t];
    int v = c;
    #pragma unroll
    for (int o = 1; o < 64; o <<= 1){
      int u = __shfl_up(v, o);
      if (lane >= o) v += u;
    }
    rbase[t + 1] = v;       // inclusive
    rcur[t]      = v - c;   // exclusive
    if (t == 0) rbase[0] = 0;
  }
  __syncthreads();

  // pass 2: counting-sort scatter into LDS (region is L2-hot from pass 1)
  for (int j = t; j < cnt; j += 256){
    int2 ev = ep[j];
    int pos = atomicAdd(&rcur[((unsigned)ev.x) >> 17], 1);
    sorted[pos] = ev;
  }
  __syncthreads();

  // pass 3: per-node register accumulation (round-0 pattern)
  const uint2* lg = (const uint2*)logits;   // 16 uint2 per node row
  int row0 = b * BROWS;
  for (int n = w; n < BROWS; n += 4){
    int node = row0 + n;
    if (node >= N_NODES) break;             // tail bucket only
    int s = rbase[n], e = rbase[n + 1];
    float a0 = 0.f, a1 = 0.f, a2 = 0.f, a3 = 0.f;
    int i = s;
    for (; i + 16 <= e; i += 16){
      int2 e0 = sorted[i      + sel];
      int2 e1 = sorted[i + 4  + sel];
      int2 e2 = sorted[i + 8  + sel];
      int2 e3 = sorted[i + 12 + sel];
      uint2 u0 = lg[((size_t)(e0.x & 0x1FFFF) << 4) + h];
      uint2 u1 = lg[((size_t)(e1.x & 0x1FFFF) << 4) + h];
      uint2 u2 = lg[((size_t)(e2.x & 0x1FFFF) << 4) + h];
      uint2 u3 = lg[((size_t)(e3.x & 0x1FFFF) << 4) + h];
      float v0 = __int_as_float(e0.y), v1 = __int_as_float(e1.y);
      float v2 = __int_as_float(e2.y), v3 = __int_as_float(e3.y);
      a0 = fmaf(v0, bflo(u0.x), a0); a1 = fmaf(v0, bfhi(u0.x), a1);
      a2 = fmaf(v0, bflo(u0.y), a2); a3 = fmaf(v0, bfhi(u0.y), a3);
      a0 = fmaf(v1, bflo(u1.x), a0); a1 = fmaf(v1, bfhi(u1.x), a1);
      a2 = fmaf(v1, bflo(u1.y), a2); a3 = fmaf(v1, bfhi(u1.y), a3);
      a0 = fmaf(v2, bflo(u2.x), a0); a1 = fmaf(v2, bfhi(u2.x), a1);
      a2 = fmaf(v2, bflo(u2.y), a2); a3 = fmaf(v2, bfhi(u2.y), a3);
      a0 = fmaf(v3, bflo(u3.x), a0); a1 = fmaf(v3, bfhi(u3.x), a1);
      a2 = fmaf(v3, bflo(u3.y), a2); a3 = fmaf(v3, bfhi(u3.y), a3);
    }
    for (; i < e; i += 4){
      int idx = i + sel;
      int col = 0; float v = 0.f;
      if (idx < e){ int2 ev = sorted[idx]; col = ev.x & 0x1FFFF; v = __int_as_float(ev.y); }
      uint2 u = lg[((size_t)col << 4) + h];
      a0 = fmaf(v, bflo(u.x), a0); a1 = fmaf(v, bfhi(u.x), a1);
      a2 = fmaf(v, bflo(u.y), a2); a3 = fmaf(v, bfhi(u.y), a3);
    }
    a0 += __shfl_xor(a0, 16); a0 += __shfl_xor(a0, 32);
    a1 += __shfl_xor(a1, 16); a1 += __shfl_xor(a1, 32);
    a2 += __shfl_xor(a2, 16); a2 += __shfl_xor(a2, 32);
    a3 += __shfl_xor(a3, 16); a3 += __shfl_xor(a3, 32);
    if (sel == 0){
      float4* op = (float4*)(out + (size_t)node * NCLS);
      op[h] = make_float4(a0, a1, a2, a3);
    }
  }
}

// Overflow side-list: applied with global atomics after bucket_agg has
// written out. cnt==0 in practice -> 256 blocks exit immediately.
__global__ __launch_bounds__(256) void ovf_apply(
    const int* __restrict__ ovf_cnt, const int4* __restrict__ ovf,
    const unsigned short* __restrict__ logits, float* __restrict__ out){
  int cnt = ovf_cnt[0];
  if (cnt > OVF_CAP) cnt = OVF_CAP;
  long total = (long)cnt * 64;
  for (long i = (long)blockIdx.x * 256 + threadIdx.x; i < total; i += (long)gridDim.x * 256){
    int e = (int)(i >> 6), c = (int)(i & 63);
    int4 ev = ovf[e];
    float lv = bflo(logits[((size_t)ev.y << 6) + c]);
    atomicAdd(&out[((size_t)ev.x << 6) + c], __int_as_float(ev.z) * lv);
  }
}

// Fallback if workspace is too small: direct atomic scatter.
__global__ void scatter_atomic(const int* __restrict__ rows, const int* __restrict__ cols,
                               const float* __restrict__ vals,
                               const unsigned short* __restrict__ logits,
                               float* __restrict__ out){
  long g = (long)blockIdx.x * 256 + threadIdx.x;
  int e = (int)(g >> 6), c = (int)(g & 63);
  if (e < N_EDGES){
    float lv = __uint_as_float(((unsigned)logits[(size_t)cols[e] * NCLS + c]) << 16);
    atomicAdd(&out[(size_t)rows[e] * NCLS + c], vals[e] * lv);
  }
}

extern "C" void kernel_launch(void* const* d_in, const int* in_sizes, int n_in,
                              void* d_out, int out_size, void* d_ws, size_t ws_size,
                              hipStream_t stream){
  const float* X     = (const float*)d_in[0];
  const int*   erows = (const int*)  d_in[1];
  const int*   ecols = (const int*)  d_in[2];
  const float* evals = (const float*)d_in[3];
  const float* W1    = (const float*)d_in[4];
  const float* b1    = (const float*)d_in[5];
  const float* W2    = (const float*)d_in[6];
  const float* b2    = (const float*)d_in[7];
  float* out = (float*)d_out;

  char* ws = (char*)d_ws;
  size_t off = 0;
  auto alloc = [&](size_t bytes) -> char* {
    char* p = ws + off;
    off = (off + bytes + 255) & ~(size_t)255;
    return p;
  };
  unsigned short* logits = (unsigned short*)alloc((size_t)N_NODES * NCLS * 2); // 12.8 MB
  unsigned short* w1f    = (unsigned short*)alloc(16*4*64*8 * 2);
  unsigned short* w2f    = (unsigned short*)alloc(2*4*64*8 * 2);
  int*  bcur = (int*)alloc((size_t)(NBKT*16 + 16) * 4);   // padded cursors + ovf_cnt
  int*  ovfc = bcur + NBKT*16;
  int4* ovf  = (int4*)alloc((size_t)OVF_CAP * 16);
  int2* ebkt = (int2*)alloc((size_t)NBKT * CAP * 8);      // 30.4 MB fixed-cap regions
  size_t full_need = off;   // ~44 MB

  prep_weights<<<144, 256, 0, stream>>>(W1, W2, w1f, w2f, bcur);
  mlp_kernel<<<(N_NODES + 63) / 64, 256, 0, stream>>>(X, b1, b2, w1f, w2f, logits);

  if (ws_size >= full_need){
    bucket_scatter<<<(N_EDGES + CHUNK - 1) / CHUNK, 256, 0, stream>>>(
        erows, ecols, evals, bcur, ovfc, ovf, ebkt);
    bucket_agg<<<NBKT, 256, 0, stream>>>(bcur, ebkt, logits, out);
    ovf_apply<<<256, 256, 0, stream>>>(ovfc, ovf, logits, out);
  } else {
    hipMemsetAsync(out, 0, (size_t)N_NODES * NCLS * 4, stream);
    scatter_atomic<<<(int)(((long)N_EDGES * 64 + 255) / 256), 256, 0, stream>>>(
        erows, ecols, evals, logits, out);
  }
}

// Round 4
// 451.000 us; speedup vs baseline: 3.8469x; 1.0656x over previous
//
#include <hip/hip_runtime.h>
#include <hip/hip_bf16.h>
#include <stdint.h>

#define N_NODES 100000
#define N_EDGES 3200000
#define F_IN    512
#define HIDDEN  64
#define NCLS    64

#define BROWS   64                  // rows per fine bucket
#define NBKT    1563                // ceil(N_NODES / BROWS)
#define CHUNK   4096                // edges per scatter block
#define CAP     2432                // slots per fine bucket (mean 2048 + ~8.5 sigma)
#define NCOARSE 25                  // ceil(N_NODES / 4096)
#define CAP1    135168              // slots per coarse bucket (mean 131072 + ~11 sigma); 33*4096
#define C2BLKS  33                  // CAP1 / CHUNK
#define OVF_CAP 8192                // overflow side-list capacity (never hit in practice)
#define SENTINEL ((int)0x80000000)
#define NZERO   (NBKT*16 + NCOARSE*16 + 16)

typedef float v4f __attribute__((ext_vector_type(4)));
typedef short v8s __attribute__((ext_vector_type(8)));

// fp32 -> bf16 bits, round-to-nearest-even
__device__ __forceinline__ unsigned short f2bf(float f){
  unsigned u = __float_as_uint(f);
  u += 0x7fffu + ((u >> 16) & 1u);
  return (unsigned short)(u >> 16);
}
__device__ __forceinline__ float bflo(unsigned u){ return __uint_as_float(u << 16); }
__device__ __forceinline__ float bfhi(unsigned u){ return __uint_as_float(u & 0xffff0000u); }

// ---------------------------------------------------------------------------
// Pre-pack W1/W2 into MFMA B-fragment order; also zero all cursors (fine +
// coarse + ovf counter) -> no memset dispatch.
// ---------------------------------------------------------------------------
__global__ void prep_weights(const float* __restrict__ W1, const float* __restrict__ W2,
                             unsigned short* __restrict__ w1f, unsigned short* __restrict__ w2f,
                             int* __restrict__ zeroc){
  int t = blockIdx.x * 256 + threadIdx.x;
  if (t < NZERO) zeroc[t] = 0;
  if (t < 16*4*64*8){
    int j = t & 7, lane = (t >> 3) & 63, nt = (t >> 9) & 3, ks = t >> 11;
    int m = lane & 15, q = lane >> 4;
    int k = ks*32 + q*8 + j, n = nt*16 + m;
    w1f[t] = f2bf(W1[k*HIDDEN + n]);
  } else {
    int u = t - 16*4*64*8;
    if (u < 2*4*64*8){
      int j = u & 7, lane = (u >> 3) & 63, nt = (u >> 9) & 3, ks = u >> 11;
      int m = lane & 15, q = lane >> 4;
      int k = ks*32 + q*8 + j, n = nt*16 + m;
      w2f[u] = f2bf(W2[k*NCLS + n]);
    }
  }
}

// ---------------------------------------------------------------------------
// Fused MLP: logits(bf16) = relu(X@W1+b1)@W2+b2. One wave = 16 nodes.
// C/D layout: col=lane&15, row=quad*4+reg (measured, m89/m91).
// ---------------------------------------------------------------------------
__global__ __launch_bounds__(256) void mlp_kernel(
    const float* __restrict__ X, const float* __restrict__ b1,
    const float* __restrict__ b2,
    const unsigned short* __restrict__ w1f, const unsigned short* __restrict__ w2f,
    unsigned short* __restrict__ logits){
  __shared__ __align__(16) float lds[4][16][68];
  int tid  = threadIdx.x;
  int wid  = tid >> 6, lane = tid & 63;
  int m    = lane & 15, q = lane >> 4;
  int base = blockIdx.x * 64 + wid * 16;
  if (base > N_NODES - 16) base = N_NODES - 16;   // tail waves redo last tile (benign)

  const float* rp = X + (size_t)(base + m) * F_IN + q * 8;
  const v8s* w1v = (const v8s*)w1f;
  const v8s* w2v = (const v8s*)w2f;

  v4f a0c = {0,0,0,0}, a1c = {0,0,0,0}, a2c = {0,0,0,0}, a3c = {0,0,0,0};
  #pragma unroll
  for (int ks = 0; ks < 16; ++ks){
    const float4* pa = (const float4*)(rp + ks * 32);
    float4 x0 = pa[0], x1 = pa[1];
    v8s af;
    af[0]=(short)f2bf(x0.x); af[1]=(short)f2bf(x0.y); af[2]=(short)f2bf(x0.z); af[3]=(short)f2bf(x0.w);
    af[4]=(short)f2bf(x1.x); af[5]=(short)f2bf(x1.y); af[6]=(short)f2bf(x1.z); af[7]=(short)f2bf(x1.w);
    a0c = __builtin_amdgcn_mfma_f32_16x16x32_bf16(af, w1v[(ks*4+0)*64 + lane], a0c, 0,0,0);
    a1c = __builtin_amdgcn_mfma_f32_16x16x32_bf16(af, w1v[(ks*4+1)*64 + lane], a1c, 0,0,0);
    a2c = __builtin_amdgcn_mfma_f32_16x16x32_bf16(af, w1v[(ks*4+2)*64 + lane], a2c, 0,0,0);
    a3c = __builtin_amdgcn_mfma_f32_16x16x32_bf16(af, w1v[(ks*4+3)*64 + lane], a3c, 0,0,0);
  }

  float b1v0 = b1[m], b1v1 = b1[16+m], b1v2 = b1[32+m], b1v3 = b1[48+m];
  #pragma unroll
  for (int r = 0; r < 4; ++r){
    int row = q*4 + r;
    lds[wid][row][     m] = fmaxf(a0c[r] + b1v0, 0.f);
    lds[wid][row][16 + m] = fmaxf(a1c[r] + b1v1, 0.f);
    lds[wid][row][32 + m] = fmaxf(a2c[r] + b1v2, 0.f);
    lds[wid][row][48 + m] = fmaxf(a3c[r] + b1v3, 0.f);
  }
  __syncthreads();

  v4f c0 = {0,0,0,0}, c1 = {0,0,0,0}, c2 = {0,0,0,0}, c3 = {0,0,0,0};
  #pragma unroll
  for (int k2 = 0; k2 < 2; ++k2){
    const float4* ph = (const float4*)&lds[wid][m][k2*32 + q*8];
    float4 h0 = ph[0], h1 = ph[1];
    v8s af;
    af[0]=(short)f2bf(h0.x); af[1]=(short)f2bf(h0.y); af[2]=(short)f2bf(h0.z); af[3]=(short)f2bf(h0.w);
    af[4]=(short)f2bf(h1.x); af[5]=(short)f2bf(h1.y); af[6]=(short)f2bf(h1.z); af[7]=(short)f2bf(h1.w);
    c0 = __builtin_amdgcn_mfma_f32_16x16x32_bf16(af, w2v[(k2*4+0)*64 + lane], c0, 0,0,0);
    c1 = __builtin_amdgcn_mfma_f32_16x16x32_bf16(af, w2v[(k2*4+1)*64 + lane], c1, 0,0,0);
    c2 = __builtin_amdgcn_mfma_f32_16x16x32_bf16(af, w2v[(k2*4+2)*64 + lane], c2, 0,0,0);
    c3 = __builtin_amdgcn_mfma_f32_16x16x32_bf16(af, w2v[(k2*4+3)*64 + lane], c3, 0,0,0);
  }

  float b2v0 = b2[m], b2v1 = b2[16+m], b2v2 = b2[32+m], b2v3 = b2[48+m];
  unsigned short* lp = logits + (size_t)base * NCLS;
  #pragma unroll
  for (int r = 0; r < 4; ++r){
    int row = q*4 + r;
    lp[row*NCLS +      m] = f2bf(c0[r] + b2v0);
    lp[row*NCLS + 16 + m] = f2bf(c1[r] + b2v1);
    lp[row*NCLS + 32 + m] = f2bf(c2[r] + b2v2);
    lp[row*NCLS + 48 + m] = f2bf(c3[r] + b2v3);
  }
}

// ---------------------------------------------------------------------------
// Level-1 scatter: edges -> 25 coarse buckets (4096 rows each). Write runs
// average 4096/25 ~ 164 edges = 1.3 KB contiguous -> fully coalesced, and
// only 25 global cursor atomics per block (vs ~1350 with 1563 fine buckets:
// that cross-XCD ping-pong + 21 B write runs were the r1-r3 scatter cost).
// Payload: localrow12 << 17 | col17, val.
// ---------------------------------------------------------------------------
__global__ __launch_bounds__(256) void scat1(
    const int* __restrict__ rows, const int* __restrict__ cols,
    const float* __restrict__ vals, int* __restrict__ c1cur,
    int* __restrict__ ovf_cnt, int4* __restrict__ ovf,
    int2* __restrict__ ebkt1){
  __shared__ int  lcnt[32];
  __shared__ int  lbase[32];
  __shared__ int2 stage[CHUNK];     // 32 KB
  __shared__ int  sdst[CHUNK];      // 16 KB
  int t = threadIdx.x;
  int base = blockIdx.x * CHUNK;
  int cnt  = min(CHUNK, N_EDGES - base);

  if (t < 32) lcnt[t] = 0;
  __syncthreads();

  int r[16];
  #pragma unroll
  for (int k = 0; k < 16; ++k){
    int li = t + k*256;
    if (li < cnt){
      r[k] = rows[base + li];
      atomicAdd(&lcnt[r[k] >> 12], 1);
    } else r[k] = -1;
  }
  __syncthreads();

  if (t < 32){
    int cme = lcnt[t];
    int v = cme;
    #pragma unroll
    for (int o = 1; o < 32; o <<= 1){
      int u = __shfl_up(v, o);
      if (t >= o) v += u;
    }
    int excl = v - cme;
    if (cme){
      int g = atomicAdd(&c1cur[t*16], cme);
      lbase[t] = t*CAP1 + g - excl;
    }
    lcnt[t] = excl;                  // becomes local cursor
  }
  __syncthreads();

  #pragma unroll
  for (int k = 0; k < 16; ++k){
    if (r[k] >= 0){
      int li = t + k*256;
      int c  = cols[base + li];
      float vv = vals[base + li];
      int b  = r[k] >> 12;
      int pos = atomicAdd(&lcnt[b], 1);
      int dest = lbase[b] + pos;
      if (dest < b*CAP1 + CAP1){
        stage[pos] = make_int2(((r[k] & 4095) << 17) | c, __float_as_int(vv));
        sdst[pos]  = lbase[b];
      } else {
        sdst[pos] = SENTINEL;
        int o = atomicAdd(ovf_cnt, 1);
        if (o < OVF_CAP) ovf[o] = make_int4(r[k], c, __float_as_int(vv), 0);
      }
    }
  }
  __syncthreads();

  for (int j = t; j < cnt; j += 256){
    int d = sdst[j];
    if (d != SENTINEL) ebkt1[d + j] = stage[j];
  }
}

// ---------------------------------------------------------------------------
// Level-2 scatter: each coarse region -> its 64 nested fine buckets
// (4096 = 64*64 so fine ranges nest exactly). Sequential reads, write runs
// 4096/64 = 64 edges = 512 B coalesced, 64 cursor atomics per block.
// Converts payload to localrow6 << 17 | col17 (what bucket_agg expects).
// ---------------------------------------------------------------------------
__global__ __launch_bounds__(256) void scat2(
    const int* __restrict__ c1cur, const int2* __restrict__ ebkt1,
    int* __restrict__ bcur, int* __restrict__ ovf_cnt, int4* __restrict__ ovf,
    int2* __restrict__ ebkt){
  __shared__ int  lcnt[64];
  __shared__ int  lbase[64];
  __shared__ int2 stage[CHUNK];     // 32 KB
  __shared__ int  sdst[CHUNK];      // 16 KB
  int t = threadIdx.x;
  int c = blockIdx.x / C2BLKS;
  int k0 = blockIdx.x % C2BLKS;

  int cntc = c1cur[c*16];
  if (cntc > CAP1) cntc = CAP1;
  int start = k0 * CHUNK;
  if (start >= cntc) return;                 // uniform across block
  int cnt = min(CHUNK, cntc - start);
  const int2* src = ebkt1 + (size_t)c * CAP1 + start;

  if (t < 64) lcnt[t] = 0;
  __syncthreads();

  int2 ev[16];
  #pragma unroll
  for (int k = 0; k < 16; ++k){
    int li = t + k*256;
    if (li < cnt){
      ev[k] = src[li];
      atomicAdd(&lcnt[(((unsigned)ev[k].x) >> 17) >> 6], 1);
    } else ev[k].x = -1;
  }
  __syncthreads();

  if (t < 64){
    int cme = lcnt[t];
    int v = cme;
    #pragma unroll
    for (int o = 1; o < 64; o <<= 1){
      int u = __shfl_up(v, o);
      if (t >= o) v += u;
    }
    int excl = v - cme;
    if (cme){
      int gb = c*64 + t;                     // global fine bucket
      int g = atomicAdd(&bcur[gb*16], cme);
      lbase[t] = gb*CAP + g - excl;
    }
    lcnt[t] = excl;
  }
  __syncthreads();

  #pragma unroll
  for (int k = 0; k < 16; ++k){
    if (ev[k].x >= 0){
      unsigned x = (unsigned)ev[k].x;
      int lr12 = (int)(x >> 17);
      int fb   = lr12 >> 6;
      int pos = atomicAdd(&lcnt[fb], 1);
      int dest = lbase[fb] + pos;
      if (dest < (c*64 + fb)*CAP + CAP){
        stage[pos] = make_int2(((lr12 & 63) << 17) | (int)(x & 0x1FFFFu), ev[k].y);
        sdst[pos]  = lbase[fb];
      } else {
        sdst[pos] = SENTINEL;
        int o = atomicAdd(ovf_cnt, 1);
        if (o < OVF_CAP) ovf[o] = make_int4(c*4096 + lr12, (int)(x & 0x1FFFFu), ev[k].y, 0);
      }
    }
  }
  __syncthreads();

  for (int j = t; j < cnt; j += 256){
    int d = sdst[j];
    if (d != SENTINEL) ebkt[d + j] = stage[j];
  }
}

// ---------------------------------------------------------------------------
// Fused counting-sort + aggregate (unchanged from r3): no FP LDS atomics.
// 1) count rows (int ds_add), 2) shuffle scan, 3) LDS counting sort,
// 4) quarter-wave-per-edge register accumulate, shfl reduce, float4 store.
// ---------------------------------------------------------------------------
__global__ __launch_bounds__(256) void bucket_agg(
    const int* __restrict__ bcur, const int2* __restrict__ ebkt,
    const unsigned short* __restrict__ logits, float* __restrict__ out){
  __shared__ int2 sorted[CAP];        // 19456 B
  __shared__ int  rc[BROWS];
  __shared__ int  rbase[BROWS + 1];
  __shared__ int  rcur[BROWS];
  int b = blockIdx.x, t = threadIdx.x;
  int w = t >> 6, lane = t & 63;
  int h = lane & 15, sel = lane >> 4;

  if (t < BROWS) rc[t] = 0;
  __syncthreads();

  int cnt = bcur[b * 16];
  if (cnt > CAP) cnt = CAP;
  const int2* ep = ebkt + (size_t)b * CAP;

  for (int j = t; j < cnt; j += 256){
    int x = ((const int*)ep)[2*j];
    atomicAdd(&rc[((unsigned)x) >> 17], 1);
  }
  __syncthreads();

  if (t < BROWS){
    int c = rc[t];
    int v = c;
    #pragma unroll
    for (int o = 1; o < 64; o <<= 1){
      int u = __shfl_up(v, o);
      if (lane >= o) v += u;
    }
    rbase[t + 1] = v;
    rcur[t]      = v - c;
    if (t == 0) rbase[0] = 0;
  }
  __syncthreads();

  for (int j = t; j < cnt; j += 256){
    int2 ev = ep[j];
    int pos = atomicAdd(&rcur[((unsigned)ev.x) >> 17], 1);
    sorted[pos] = ev;
  }
  __syncthreads();

  const uint2* lg = (const uint2*)logits;
  int row0 = b * BROWS;
  for (int n = w; n < BROWS; n += 4){
    int node = row0 + n;
    if (node >= N_NODES) break;
    int s = rbase[n], e = rbase[n + 1];
    float a0 = 0.f, a1 = 0.f, a2 = 0.f, a3 = 0.f;
    int i = s;
    for (; i + 16 <= e; i += 16){
      int2 e0 = sorted[i      + sel];
      int2 e1 = sorted[i + 4  + sel];
      int2 e2 = sorted[i + 8  + sel];
      int2 e3 = sorted[i + 12 + sel];
      uint2 u0 = lg[((size_t)(e0.x & 0x1FFFF) << 4) + h];
      uint2 u1 = lg[((size_t)(e1.x & 0x1FFFF) << 4) + h];
      uint2 u2 = lg[((size_t)(e2.x & 0x1FFFF) << 4) + h];
      uint2 u3 = lg[((size_t)(e3.x & 0x1FFFF) << 4) + h];
      float v0 = __int_as_float(e0.y), v1 = __int_as_float(e1.y);
      float v2 = __int_as_float(e2.y), v3 = __int_as_float(e3.y);
      a0 = fmaf(v0, bflo(u0.x), a0); a1 = fmaf(v0, bfhi(u0.x), a1);
      a2 = fmaf(v0, bflo(u0.y), a2); a3 = fmaf(v0, bfhi(u0.y), a3);
      a0 = fmaf(v1, bflo(u1.x), a0); a1 = fmaf(v1, bfhi(u1.x), a1);
      a2 = fmaf(v1, bflo(u1.y), a2); a3 = fmaf(v1, bfhi(u1.y), a3);
      a0 = fmaf(v2, bflo(u2.x), a0); a1 = fmaf(v2, bfhi(u2.x), a1);
      a2 = fmaf(v2, bflo(u2.y), a2); a3 = fmaf(v2, bfhi(u2.y), a3);
      a0 = fmaf(v3, bflo(u3.x), a0); a1 = fmaf(v3, bfhi(u3.x), a1);
      a2 = fmaf(v3, bflo(u3.y), a2); a3 = fmaf(v3, bfhi(u3.y), a3);
    }
    for (; i < e; i += 4){
      int idx = i + sel;
      int col = 0; float v = 0.f;
      if (idx < e){ int2 evv = sorted[idx]; col = evv.x & 0x1FFFF; v = __int_as_float(evv.y); }
      uint2 u = lg[((size_t)col << 4) + h];
      a0 = fmaf(v, bflo(u.x), a0); a1 = fmaf(v, bfhi(u.x), a1);
      a2 = fmaf(v, bflo(u.y), a2); a3 = fmaf(v, bfhi(u.y), a3);
    }
    a0 += __shfl_xor(a0, 16); a0 += __shfl_xor(a0, 32);
    a1 += __shfl_xor(a1, 16); a1 += __shfl_xor(a1, 32);
    a2 += __shfl_xor(a2, 16); a2 += __shfl_xor(a2, 32);
    a3 += __shfl_xor(a3, 16); a3 += __shfl_xor(a3, 32);
    if (sel == 0){
      float4* op = (float4*)(out + (size_t)node * NCLS);
      op[h] = make_float4(a0, a1, a2, a3);
    }
  }
}

// Overflow side-list (cnt==0 in practice).
__global__ __launch_bounds__(256) void ovf_apply(
    const int* __restrict__ ovf_cnt, const int4* __restrict__ ovf,
    const unsigned short* __restrict__ logits, float* __restrict__ out){
  int cnt = ovf_cnt[0];
  if (cnt > OVF_CAP) cnt = OVF_CAP;
  long total = (long)cnt * 64;
  for (long i = (long)blockIdx.x * 256 + threadIdx.x; i < total; i += (long)gridDim.x * 256){
    int e = (int)(i >> 6), c = (int)(i & 63);
    int4 ev = ovf[e];
    float lv = bflo(logits[((size_t)ev.y << 6) + c]);
    atomicAdd(&out[((size_t)ev.x << 6) + c], __int_as_float(ev.z) * lv);
  }
}

// Fallback if workspace is too small: direct atomic scatter.
__global__ void scatter_atomic(const int* __restrict__ rows, const int* __restrict__ cols,
                               const float* __restrict__ vals,
                               const unsigned short* __restrict__ logits,
                               float* __restrict__ out){
  long g = (long)blockIdx.x * 256 + threadIdx.x;
  int e = (int)(g >> 6), c = (int)(g & 63);
  if (e < N_EDGES){
    float lv = __uint_as_float(((unsigned)logits[(size_t)cols[e] * NCLS + c]) << 16);
    atomicAdd(&out[(size_t)rows[e] * NCLS + c], vals[e] * lv);
  }
}

extern "C" void kernel_launch(void* const* d_in, const int* in_sizes, int n_in,
                              void* d_out, int out_size, void* d_ws, size_t ws_size,
                              hipStream_t stream){
  const float* X     = (const float*)d_in[0];
  const int*   erows = (const int*)  d_in[1];
  const int*   ecols = (const int*)  d_in[2];
  const float* evals = (const float*)d_in[3];
  const float* W1    = (const float*)d_in[4];
  const float* b1    = (const float*)d_in[5];
  const float* W2    = (const float*)d_in[6];
  const float* b2    = (const float*)d_in[7];
  float* out = (float*)d_out;

  char* ws = (char*)d_ws;
  size_t off = 0;
  auto alloc = [&](size_t bytes) -> char* {
    char* p = ws + off;
    off = (off + bytes + 255) & ~(size_t)255;
    return p;
  };
  unsigned short* logits = (unsigned short*)alloc((size_t)N_NODES * NCLS * 2); // 12.8 MB
  unsigned short* w1f    = (unsigned short*)alloc(16*4*64*8 * 2);
  unsigned short* w2f    = (unsigned short*)alloc(2*4*64*8 * 2);
  int*  bcur  = (int*)alloc((size_t)NZERO * 4);   // fine cursors | coarse cursors | ovf_cnt
  int*  c1cur = bcur + NBKT*16;
  int*  ovfc  = bcur + NBKT*16 + NCOARSE*16;
  int4* ovf   = (int4*)alloc((size_t)OVF_CAP * 16);
  int2* ebkt1 = (int2*)alloc((size_t)NCOARSE * CAP1 * 8);  // 27.0 MB coarse regions
  int2* ebkt  = (int2*)alloc((size_t)NBKT * CAP * 8);      // 30.4 MB fine regions
  size_t full_need = off;   // ~71 MB

  prep_weights<<<144, 256, 0, stream>>>(W1, W2, w1f, w2f, bcur);
  mlp_kernel<<<(N_NODES + 63) / 64, 256, 0, stream>>>(X, b1, b2, w1f, w2f, logits);

  if (ws_size >= full_need){
    scat1<<<(N_EDGES + CHUNK - 1) / CHUNK, 256, 0, stream>>>(
        erows, ecols, evals, c1cur, ovfc, ovf, ebkt1);
    scat2<<<NCOARSE * C2BLKS, 256, 0, stream>>>(
        c1cur, ebkt1, bcur, ovfc, ovf, ebkt);
    bucket_agg<<<NBKT, 256, 0, stream>>>(bcur, ebkt, logits, out);
    ovf_apply<<<256, 256, 0, stream>>>(ovfc, ovf, logits, out);
  } else {
    hipMemsetAsync(out, 0, (size_t)N_NODES * NCLS * 4, stream);
    scatter_atomic<<<(int)(((long)N_EDGES * 64 + 255) / 256), 256, 0, stream>>>(
        erows, ecols, evals, logits, out);
  }
}

// Round 5
// 436.716 us; speedup vs baseline: 3.9727x; 1.0327x over previous
//
#include <hip/hip_runtime.h>
#include <hip/hip_bf16.h>
#include <stdint.h>

#define N_NODES 100000
#define N_EDGES 3200000
#define F_IN    512
#define HIDDEN  64
#define NCLS    64

#define BROWS   64                  // rows per fine bucket
#define NBKT    1563                // ceil(N_NODES / BROWS)
#define CHUNK   4096                // edges per scat1 block
#define CHUNK2  2048                // edges per scat2 block (keeps fused K2 LDS at 25 KB)
#define CAP     2432                // slots per fine bucket (mean 2048 + ~8.5 sigma)
#define NCOARSE 25                  // ceil(N_NODES / 4096)
#define CAP1    135168              // slots per coarse bucket; 66*2048
#define C2BLKS  66                  // CAP1 / CHUNK2
#define OVF_CAP 8192                // overflow side-list capacity (never hit in practice)
#define SENTINEL ((int)0x80000000)
#define NZERO   (NBKT*16 + NCOARSE*16 + 16)

#define PREP_BLKS 144
#define SC1_BLKS  782               // ceil(N_EDGES / CHUNK)
#define MLP_BLKS  1563              // ceil(N_NODES / 64)
#define SC2_BLKS  (NCOARSE * C2BLKS)  // 1650

typedef float v4f __attribute__((ext_vector_type(4)));
typedef short v8s __attribute__((ext_vector_type(8)));

// fp32 -> bf16 bits, round-to-nearest-even
__device__ __forceinline__ unsigned short f2bf(float f){
  unsigned u = __float_as_uint(f);
  u += 0x7fffu + ((u >> 16) & 1u);
  return (unsigned short)(u >> 16);
}
__device__ __forceinline__ float bflo(unsigned u){ return __uint_as_float(u << 16); }
__device__ __forceinline__ float bfhi(unsigned u){ return __uint_as_float(u & 0xffff0000u); }

// ---------------------------------------------------------------------------
// K1 = prep_weights (blocks [0,144)) || scat1 (blocks [144, 144+782)).
// prep packs W1/W2 into MFMA B-fragment order. scat1 bins edges into 25
// coarse buckets (4096 rows each): write runs ~164 edges = 1.3 KB coalesced,
// 25 cursor atomics/block. Cursor zeroing moved to a hipMemsetAsync (prep
// zeroing here would race scat1's atomics within the same kernel).
// Payload: localrow12 << 17 | col17, val.
// ---------------------------------------------------------------------------
__global__ __launch_bounds__(256) void k1(
    const int* __restrict__ rows, const int* __restrict__ cols,
    const float* __restrict__ vals, int* __restrict__ c1cur,
    int* __restrict__ ovf_cnt, int4* __restrict__ ovf,
    int2* __restrict__ ebkt1,
    const float* __restrict__ W1, const float* __restrict__ W2,
    unsigned short* __restrict__ w1f, unsigned short* __restrict__ w2f){
  __shared__ int  lcnt[32];
  __shared__ int  lbase[32];
  __shared__ int2 stage[CHUNK];     // 32 KB
  __shared__ int  sdst[CHUNK];      // 16 KB
  int t = threadIdx.x;

  if (blockIdx.x < PREP_BLKS){
    int g = blockIdx.x * 256 + t;
    if (g < 16*4*64*8){
      int j = g & 7, lane = (g >> 3) & 63, nt = (g >> 9) & 3, ks = g >> 11;
      int m = lane & 15, q = lane >> 4;
      int k = ks*32 + q*8 + j, n = nt*16 + m;
      w1f[g] = f2bf(W1[k*HIDDEN + n]);
    } else {
      int u = g - 16*4*64*8;
      if (u < 2*4*64*8){
        int j = u & 7, lane = (u >> 3) & 63, nt = (u >> 9) & 3, ks = u >> 11;
        int m = lane & 15, q = lane >> 4;
        int k = ks*32 + q*8 + j, n = nt*16 + m;
        w2f[u] = f2bf(W2[k*NCLS + n]);
      }
    }
    return;
  }

  int base = (blockIdx.x - PREP_BLKS) * CHUNK;
  int cnt  = min(CHUNK, N_EDGES - base);

  if (t < 32) lcnt[t] = 0;
  __syncthreads();

  int r[16];
  #pragma unroll
  for (int k = 0; k < 16; ++k){
    int li = t + k*256;
    if (li < cnt){
      r[k] = rows[base + li];
      atomicAdd(&lcnt[r[k] >> 12], 1);
    } else r[k] = -1;
  }
  __syncthreads();

  if (t < 32){
    int cme = lcnt[t];
    int v = cme;
    #pragma unroll
    for (int o = 1; o < 32; o <<= 1){
      int u = __shfl_up(v, o);
      if (t >= o) v += u;
    }
    int excl = v - cme;
    if (cme){
      int g = atomicAdd(&c1cur[t*16], cme);
      lbase[t] = t*CAP1 + g - excl;
    }
    lcnt[t] = excl;                  // becomes local cursor
  }
  __syncthreads();

  #pragma unroll
  for (int k = 0; k < 16; ++k){
    if (r[k] >= 0){
      int li = t + k*256;
      int c  = cols[base + li];
      float vv = vals[base + li];
      int b  = r[k] >> 12;
      int pos = atomicAdd(&lcnt[b], 1);
      int dest = lbase[b] + pos;
      if (dest < b*CAP1 + CAP1){
        stage[pos] = make_int2(((r[k] & 4095) << 17) | c, __float_as_int(vv));
        sdst[pos]  = lbase[b];
      } else {
        sdst[pos] = SENTINEL;
        int o = atomicAdd(ovf_cnt, 1);
        if (o < OVF_CAP) ovf[o] = make_int4(r[k], c, __float_as_int(vv), 0);
      }
    }
  }
  __syncthreads();

  for (int j = t; j < cnt; j += 256){
    int d = sdst[j];
    if (d != SENTINEL) ebkt1[d + j] = stage[j];
  }
}

// ---------------------------------------------------------------------------
// K2 = mlp (blocks [0,1563)) || scat2 (blocks [1563, 1563+1650)).
// Shared memory is a 25 KB union: mlp uses 17.4 KB as float[4][16][68];
// scat2 uses stage/sdst/lcnt/lbase. mlp and scat2 are data-independent; the
// fusion rides scat2's 51 MB of traffic under mlp's BW-bound 205 MB X read.
// ---------------------------------------------------------------------------
__global__ __launch_bounds__(256) void k2(
    const float* __restrict__ X, const float* __restrict__ b1,
    const float* __restrict__ b2,
    const unsigned short* __restrict__ w1f, const unsigned short* __restrict__ w2f,
    unsigned short* __restrict__ logits,
    const int* __restrict__ c1cur, const int2* __restrict__ ebkt1,
    int* __restrict__ bcur, int* __restrict__ ovf_cnt, int4* __restrict__ ovf,
    int2* __restrict__ ebkt){
  __shared__ __align__(16) char smem[25088];
  int tid = threadIdx.x;

  if (blockIdx.x < MLP_BLKS){
    // ---------------- MLP: logits(bf16) = relu(X@W1+b1)@W2+b2 --------------
    float (*lds)[16][68] = (float (*)[16][68])smem;
    int wid  = tid >> 6, lane = tid & 63;
    int m    = lane & 15, q = lane >> 4;
    int base = blockIdx.x * 64 + wid * 16;
    if (base > N_NODES - 16) base = N_NODES - 16;   // tail waves redo last tile (benign)

    const float* rp = X + (size_t)(base + m) * F_IN + q * 8;
    const v8s* w1v = (const v8s*)w1f;
    const v8s* w2v = (const v8s*)w2f;

    v4f a0c = {0,0,0,0}, a1c = {0,0,0,0}, a2c = {0,0,0,0}, a3c = {0,0,0,0};
    #pragma unroll
    for (int ks = 0; ks < 16; ++ks){
      const float4* pa = (const float4*)(rp + ks * 32);
      float4 x0 = pa[0], x1 = pa[1];
      v8s af;
      af[0]=(short)f2bf(x0.x); af[1]=(short)f2bf(x0.y); af[2]=(short)f2bf(x0.z); af[3]=(short)f2bf(x0.w);
      af[4]=(short)f2bf(x1.x); af[5]=(short)f2bf(x1.y); af[6]=(short)f2bf(x1.z); af[7]=(short)f2bf(x1.w);
      a0c = __builtin_amdgcn_mfma_f32_16x16x32_bf16(af, w1v[(ks*4+0)*64 + lane], a0c, 0,0,0);
      a1c = __builtin_amdgcn_mfma_f32_16x16x32_bf16(af, w1v[(ks*4+1)*64 + lane], a1c, 0,0,0);
      a2c = __builtin_amdgcn_mfma_f32_16x16x32_bf16(af, w1v[(ks*4+2)*64 + lane], a2c, 0,0,0);
      a3c = __builtin_amdgcn_mfma_f32_16x16x32_bf16(af, w1v[(ks*4+3)*64 + lane], a3c, 0,0,0);
    }

    float b1v0 = b1[m], b1v1 = b1[16+m], b1v2 = b1[32+m], b1v3 = b1[48+m];
    #pragma unroll
    for (int r = 0; r < 4; ++r){
      int row = q*4 + r;
      lds[wid][row][     m] = fmaxf(a0c[r] + b1v0, 0.f);
      lds[wid][row][16 + m] = fmaxf(a1c[r] + b1v1, 0.f);
      lds[wid][row][32 + m] = fmaxf(a2c[r] + b1v2, 0.f);
      lds[wid][row][48 + m] = fmaxf(a3c[r] + b1v3, 0.f);
    }
    __syncthreads();

    v4f c0 = {0,0,0,0}, c1 = {0,0,0,0}, c2 = {0,0,0,0}, c3 = {0,0,0,0};
    #pragma unroll
    for (int k2i = 0; k2i < 2; ++k2i){
      const float4* ph = (const float4*)&lds[wid][m][k2i*32 + q*8];
      float4 h0 = ph[0], h1 = ph[1];
      v8s af;
      af[0]=(short)f2bf(h0.x); af[1]=(short)f2bf(h0.y); af[2]=(short)f2bf(h0.z); af[3]=(short)f2bf(h0.w);
      af[4]=(short)f2bf(h1.x); af[5]=(short)f2bf(h1.y); af[6]=(short)f2bf(h1.z); af[7]=(short)f2bf(h1.w);
      c0 = __builtin_amdgcn_mfma_f32_16x16x32_bf16(af, w2v[(k2i*4+0)*64 + lane], c0, 0,0,0);
      c1 = __builtin_amdgcn_mfma_f32_16x16x32_bf16(af, w2v[(k2i*4+1)*64 + lane], c1, 0,0,0);
      c2 = __builtin_amdgcn_mfma_f32_16x16x32_bf16(af, w2v[(k2i*4+2)*64 + lane], c2, 0,0,0);
      c3 = __builtin_amdgcn_mfma_f32_16x16x32_bf16(af, w2v[(k2i*4+3)*64 + lane], c3, 0,0,0);
    }

    float b2v0 = b2[m], b2v1 = b2[16+m], b2v2 = b2[32+m], b2v3 = b2[48+m];
    unsigned short* lp = logits + (size_t)base * NCLS;
    #pragma unroll
    for (int r = 0; r < 4; ++r){
      int row = q*4 + r;
      lp[row*NCLS +      m] = f2bf(c0[r] + b2v0);
      lp[row*NCLS + 16 + m] = f2bf(c1[r] + b2v1);
      lp[row*NCLS + 32 + m] = f2bf(c2[r] + b2v2);
      lp[row*NCLS + 48 + m] = f2bf(c3[r] + b2v3);
    }
    return;
  }

  // ------------- scat2: coarse region chunk -> 64 nested fine buckets ------
  int2* stage = (int2*)smem;               // 16384 B
  int*  sdst  = (int*)(smem + 16384);      //  8192 B
  int*  lcnt  = (int*)(smem + 24576);      //   256 B
  int*  lbase = (int*)(smem + 24832);      //   256 B
  int sbid = blockIdx.x - MLP_BLKS;
  int c  = sbid / C2BLKS;
  int k0 = sbid % C2BLKS;

  int cntc = c1cur[c*16];
  if (cntc > CAP1) cntc = CAP1;
  int start = k0 * CHUNK2;
  if (start >= cntc) return;                 // uniform across block
  int cnt = min(CHUNK2, cntc - start);
  const int2* src = ebkt1 + (size_t)c * CAP1 + start;

  if (tid < 64) lcnt[tid] = 0;
  __syncthreads();

  int2 ev[8];
  #pragma unroll
  for (int k = 0; k < 8; ++k){
    int li = tid + k*256;
    if (li < cnt){
      ev[k] = src[li];
      atomicAdd(&lcnt[(((unsigned)ev[k].x) >> 17) >> 6], 1);
    } else ev[k].x = -1;
  }
  __syncthreads();

  if (tid < 64){
    int cme = lcnt[tid];
    int v = cme;
    #pragma unroll
    for (int o = 1; o < 64; o <<= 1){
      int u = __shfl_up(v, o);
      if (tid >= o) v += u;
    }
    int excl = v - cme;
    if (cme){
      int gb = c*64 + tid;                   // global fine bucket
      int g = atomicAdd(&bcur[gb*16], cme);
      lbase[tid] = gb*CAP + g - excl;
    }
    lcnt[tid] = excl;
  }
  __syncthreads();

  #pragma unroll
  for (int k = 0; k < 8; ++k){
    if (ev[k].x >= 0){
      unsigned x = (unsigned)ev[k].x;
      int lr12 = (int)(x >> 17);
      int fb   = lr12 >> 6;
      int pos = atomicAdd(&lcnt[fb], 1);
      int dest = lbase[fb] + pos;
      if (dest < (c*64 + fb)*CAP + CAP){
        stage[pos] = make_int2(((lr12 & 63) << 17) | (int)(x & 0x1FFFFu), ev[k].y);
        sdst[pos]  = lbase[fb];
      } else {
        sdst[pos] = SENTINEL;
        int o = atomicAdd(ovf_cnt, 1);
        if (o < OVF_CAP) ovf[o] = make_int4(c*4096 + lr12, (int)(x & 0x1FFFFu), ev[k].y, 0);
      }
    }
  }
  __syncthreads();

  for (int j = tid; j < cnt; j += 256){
    int d = sdst[j];
    if (d != SENTINEL) ebkt[d + j] = stage[j];
  }
}

// ---------------------------------------------------------------------------
// K3: fused counting-sort + aggregate (two-pass, proven in r3/r4), with the
// overflow fix-up folded in: each block patches its own rows from the (in
// practice empty) side list before its non-atomic float4 store -> no 6th
// dispatch, no out atomics.
// ---------------------------------------------------------------------------
__global__ __launch_bounds__(256) void bucket_agg(
    const int* __restrict__ bcur, const int2* __restrict__ ebkt,
    const unsigned short* __restrict__ logits, float* __restrict__ out,
    const int* __restrict__ ovf_cnt, const int4* __restrict__ ovfl){
  __shared__ int2 sorted[CAP];        // 19456 B
  __shared__ int  rc[BROWS];
  __shared__ int  rbase[BROWS + 1];
  __shared__ int  rcur[BROWS];
  int b = blockIdx.x, t = threadIdx.x;
  int w = t >> 6, lane = t & 63;
  int h = lane & 15, sel = lane >> 4;

  if (t < BROWS) rc[t] = 0;
  __syncthreads();

  int cnt = bcur[b * 16];
  if (cnt > CAP) cnt = CAP;
  const int2* ep = ebkt + (size_t)b * CAP;
  int ocnt = ovf_cnt[0];
  if (ocnt > OVF_CAP) ocnt = OVF_CAP;

  for (int j = t; j < cnt; j += 256){
    int x = ((const int*)ep)[2*j];
    atomicAdd(&rc[((unsigned)x) >> 17], 1);
  }
  __syncthreads();

  if (t < BROWS){
    int c = rc[t];
    int v = c;
    #pragma unroll
    for (int o = 1; o < 64; o <<= 1){
      int u = __shfl_up(v, o);
      if (lane >= o) v += u;
    }
    rbase[t + 1] = v;
    rcur[t]      = v - c;
    if (t == 0) rbase[0] = 0;
  }
  __syncthreads();

  for (int j = t; j < cnt; j += 256){
    int2 ev = ep[j];
    int pos = atomicAdd(&rcur[((unsigned)ev.x) >> 17], 1);
    sorted[pos] = ev;
  }
  __syncthreads();

  const uint2* lg = (const uint2*)logits;
  int row0 = b * BROWS;
  for (int n = w; n < BROWS; n += 4){
    int node = row0 + n;
    if (node >= N_NODES) break;
    int s = rbase[n], e = rbase[n + 1];
    float a0 = 0.f, a1 = 0.f, a2 = 0.f, a3 = 0.f;
    int i = s;
    for (; i + 16 <= e; i += 16){
      int2 e0 = sorted[i      + sel];
      int2 e1 = sorted[i + 4  + sel];
      int2 e2 = sorted[i + 8  + sel];
      int2 e3 = sorted[i + 12 + sel];
      uint2 u0 = lg[((size_t)(e0.x & 0x1FFFF) << 4) + h];
      uint2 u1 = lg[((size_t)(e1.x & 0x1FFFF) << 4) + h];
      uint2 u2 = lg[((size_t)(e2.x & 0x1FFFF) << 4) + h];
      uint2 u3 = lg[((size_t)(e3.x & 0x1FFFF) << 4) + h];
      float v0 = __int_as_float(e0.y), v1 = __int_as_float(e1.y);
      float v2 = __int_as_float(e2.y), v3 = __int_as_float(e3.y);
      a0 = fmaf(v0, bflo(u0.x), a0); a1 = fmaf(v0, bfhi(u0.x), a1);
      a2 = fmaf(v0, bflo(u0.y), a2); a3 = fmaf(v0, bfhi(u0.y), a3);
      a0 = fmaf(v1, bflo(u1.x), a0); a1 = fmaf(v1, bfhi(u1.x), a1);
      a2 = fmaf(v1, bflo(u1.y), a2); a3 = fmaf(v1, bfhi(u1.y), a3);
      a0 = fmaf(v2, bflo(u2.x), a0); a1 = fmaf(v2, bfhi(u2.x), a1);
      a2 = fmaf(v2, bflo(u2.y), a2); a3 = fmaf(v2, bfhi(u2.y), a3);
      a0 = fmaf(v3, bflo(u3.x), a0); a1 = fmaf(v3, bfhi(u3.x), a1);
      a2 = fmaf(v3, bflo(u3.y), a2); a3 = fmaf(v3, bfhi(u3.y), a3);
    }
    for (; i < e; i += 4){
      int idx = i + sel;
      int col = 0; float v = 0.f;
      if (idx < e){ int2 evv = sorted[idx]; col = evv.x & 0x1FFFF; v = __int_as_float(evv.y); }
      uint2 u = lg[((size_t)col << 4) + h];
      a0 = fmaf(v, bflo(u.x), a0); a1 = fmaf(v, bfhi(u.x), a1);
      a2 = fmaf(v, bflo(u.y), a2); a3 = fmaf(v, bfhi(u.y), a3);
    }
    a0 += __shfl_xor(a0, 16); a0 += __shfl_xor(a0, 32);
    a1 += __shfl_xor(a1, 16); a1 += __shfl_xor(a1, 32);
    a2 += __shfl_xor(a2, 16); a2 += __shfl_xor(a2, 32);
    a3 += __shfl_xor(a3, 16); a3 += __shfl_xor(a3, 32);
    if (sel == 0){
      if (ocnt){                       // overflow fix-up (empty in practice)
        for (int j = 0; j < ocnt; ++j){
          int4 eo = ovfl[j];
          if (eo.x == node){
            uint2 u = lg[((size_t)eo.y << 4) + h];
            float v = __int_as_float(eo.z);
            a0 = fmaf(v, bflo(u.x), a0); a1 = fmaf(v, bfhi(u.x), a1);
            a2 = fmaf(v, bflo(u.y), a2); a3 = fmaf(v, bfhi(u.y), a3);
          }
        }
      }
      float4* op = (float4*)(out + (size_t)node * NCLS);
      op[h] = make_float4(a0, a1, a2, a3);
    }
  }
}

// Fallback if workspace is too small: direct atomic scatter.
__global__ void scatter_atomic(const int* __restrict__ rows, const int* __restrict__ cols,
                               const float* __restrict__ vals,
                               const unsigned short* __restrict__ logits,
                               float* __restrict__ out){
  long g = (long)blockIdx.x * 256 + threadIdx.x;
  int e = (int)(g >> 6), c = (int)(g & 63);
  if (e < N_EDGES){
    float lv = __uint_as_float(((unsigned)logits[(size_t)cols[e] * NCLS + c]) << 16);
    atomicAdd(&out[(size_t)rows[e] * NCLS + c], vals[e] * lv);
  }
}

extern "C" void kernel_launch(void* const* d_in, const int* in_sizes, int n_in,
                              void* d_out, int out_size, void* d_ws, size_t ws_size,
                              hipStream_t stream){
  const float* X     = (const float*)d_in[0];
  const int*   erows = (const int*)  d_in[1];
  const int*   ecols = (const int*)  d_in[2];
  const float* evals = (const float*)d_in[3];
  const float* W1    = (const float*)d_in[4];
  const float* b1    = (const float*)d_in[5];
  const float* W2    = (const float*)d_in[6];
  const float* b2    = (const float*)d_in[7];
  float* out = (float*)d_out;

  char* ws = (char*)d_ws;
  size_t off = 0;
  auto alloc = [&](size_t bytes) -> char* {
    char* p = ws + off;
    off = (off + bytes + 255) & ~(size_t)255;
    return p;
  };
  unsigned short* logits = (unsigned short*)alloc((size_t)N_NODES * NCLS * 2); // 12.8 MB
  unsigned short* w1f    = (unsigned short*)alloc(16*4*64*8 * 2);
  unsigned short* w2f    = (unsigned short*)alloc(2*4*64*8 * 2);
  int*  bcur  = (int*)alloc((size_t)NZERO * 4);   // fine cursors | coarse cursors | ovf_cnt
  int*  c1cur = bcur + NBKT*16;
  int*  ovfc  = bcur + NBKT*16 + NCOARSE*16;
  int4* ovf   = (int4*)alloc((size_t)OVF_CAP * 16);
  int2* ebkt1 = (int2*)alloc((size_t)NCOARSE * CAP1 * 8);  // 27.0 MB coarse regions
  int2* ebkt  = (int2*)alloc((size_t)NBKT * CAP * 8);      // 30.4 MB fine regions
  size_t full_need = off;   // ~71 MB

  if (ws_size >= full_need){
    hipMemsetAsync(bcur, 0, (size_t)NZERO * 4, stream);    // ~100 KB, ~2 us
    k1<<<PREP_BLKS + SC1_BLKS, 256, 0, stream>>>(
        erows, ecols, evals, c1cur, ovfc, ovf, ebkt1, W1, W2, w1f, w2f);
    k2<<<MLP_BLKS + SC2_BLKS, 256, 0, stream>>>(
        X, b1, b2, w1f, w2f, logits, c1cur, ebkt1, bcur, ovfc, ovf, ebkt);
    bucket_agg<<<NBKT, 256, 0, stream>>>(bcur, ebkt, logits, out, ovfc, ovf);
  } else {
    // prep-only grid (prep blocks are [0, PREP_BLKS)), then mlp-only grid
    k1<<<PREP_BLKS, 256, 0, stream>>>(
        erows, ecols, evals, c1cur, ovfc, ovf, ebkt1, W1, W2, w1f, w2f);
    k2<<<MLP_BLKS, 256, 0, stream>>>(
        X, b1, b2, w1f, w2f, logits, c1cur, ebkt1, bcur, ovfc, ovf, ebkt);
    hipMemsetAsync(out, 0, (size_t)N_NODES * NCLS * 4, stream);
    scatter_atomic<<<(int)(((long)N_EDGES * 64 + 255) / 256), 256, 0, stream>>>(
        erows, ecols, evals, logits, out);
  }
}

// Round 6
// 419.203 us; speedup vs baseline: 4.1387x; 1.0418x over previous
//
#include <hip/hip_runtime.h>
#include <hip/hip_bf16.h>
#include <stdint.h>

#define N_NODES 100000
#define N_EDGES 3200000
#define F_IN    512
#define HIDDEN  64
#define NCLS    64

#define BROWS   64                  // rows per fine bucket
#define NBKT    1563                // ceil(N_NODES / BROWS)
#define CHUNK   4096                // edges per scat1 block
#define CHUNK2  2048                // edges per scat2 block (keeps fused K2 LDS at 25 KB)
#define CAP     2432                // slots per fine bucket (mean 2048 + ~8.5 sigma)
#define NCOARSE 25                  // ceil(N_NODES / 4096)
#define CAP1    135168              // slots per coarse bucket; 66*2048
#define C2BLKS  66                  // CAP1 / CHUNK2
#define OVF_CAP 8192                // overflow side-list capacity (never hit in practice)
#define SENTINEL ((int)0x80000000)
#define NZERO   (NBKT*16 + NCOARSE*16 + 16)

#define PREP_BLKS 144
#define SC1_BLKS  782               // ceil(N_EDGES / CHUNK)
#define MLP_BLKS  1563              // ceil(N_NODES / 64)
#define SC2_BLKS  (NCOARSE * C2BLKS)  // 1650

typedef float v4f __attribute__((ext_vector_type(4)));
typedef short v8s __attribute__((ext_vector_type(8)));

// fp32 -> bf16 bits, manual RNE (used on cold paths only)
__device__ __forceinline__ unsigned short f2bf(float f){
  unsigned u = __float_as_uint(f);
  u += 0x7fffu + ((u >> 16) & 1u);
  return (unsigned short)(u >> 16);
}
// fp32 -> bf16 via hardware convert (compiler lowers fptrunc to v_cvt_*_bf16;
// m240: scalar cast is the fast path, do NOT hand-write cvt_pk asm)
__device__ __forceinline__ short f2bfh(float f){
  __bf16 h = (__bf16)f;
  return __builtin_bit_cast(short, h);
}
__device__ __forceinline__ float bflo(unsigned u){ return __uint_as_float(u << 16); }
__device__ __forceinline__ float bfhi(unsigned u){ return __uint_as_float(u & 0xffff0000u); }

// ---------------------------------------------------------------------------
// K1 = prep_weights (blocks [0,144)) || scat1 (blocks [144, 144+782)).
// scat1: vectorized int4/float4 edge loads; bins edges into 25 coarse
// buckets (write runs ~164 edges = 1.3 KB coalesced, 25 cursor atomics/blk).
// Payload: localrow12 << 17 | col17, val.
// ---------------------------------------------------------------------------
__global__ __launch_bounds__(256) void k1(
    const int* __restrict__ rows, const int* __restrict__ cols,
    const float* __restrict__ vals, int* __restrict__ c1cur,
    int* __restrict__ ovf_cnt, int4* __restrict__ ovf,
    int2* __restrict__ ebkt1,
    const float* __restrict__ W1, const float* __restrict__ W2,
    unsigned short* __restrict__ w1f, unsigned short* __restrict__ w2f){
  __shared__ int  lcnt[32];
  __shared__ int  lbase[32];
  __shared__ int2 stage[CHUNK];     // 32 KB
  __shared__ int  sdst[CHUNK];      // 16 KB
  int t = threadIdx.x;

  if (blockIdx.x < PREP_BLKS){
    int g = blockIdx.x * 256 + t;
    if (g < 16*4*64*8){
      int j = g & 7, lane = (g >> 3) & 63, nt = (g >> 9) & 3, ks = g >> 11;
      int m = lane & 15, q = lane >> 4;
      int k = ks*32 + q*8 + j, n = nt*16 + m;
      w1f[g] = f2bf(W1[k*HIDDEN + n]);
    } else {
      int u = g - 16*4*64*8;
      if (u < 2*4*64*8){
        int j = u & 7, lane = (u >> 3) & 63, nt = (u >> 9) & 3, ks = u >> 11;
        int m = lane & 15, q = lane >> 4;
        int k = ks*32 + q*8 + j, n = nt*16 + m;
        w2f[u] = f2bf(W2[k*NCLS + n]);
      }
    }
    return;
  }

  int base = (blockIdx.x - PREP_BLKS) * CHUNK;
  int cnt  = min(CHUNK, N_EDGES - base);   // always a multiple of 4
  int nv   = cnt >> 2;
  const int4*   rv = (const int4*)(rows + base);
  const int4*   cv = (const int4*)(cols + base);
  const float4* fv = (const float4*)(vals + base);

  if (t < 32) lcnt[t] = 0;
  __syncthreads();

  int4 rr[4];
  #pragma unroll
  for (int j = 0; j < 4; ++j){
    int li4 = t + j*256;
    if (li4 < nv){
      rr[j] = rv[li4];
      atomicAdd(&lcnt[rr[j].x >> 12], 1);
      atomicAdd(&lcnt[rr[j].y >> 12], 1);
      atomicAdd(&lcnt[rr[j].z >> 12], 1);
      atomicAdd(&lcnt[rr[j].w >> 12], 1);
    } else {
      rr[j].x = rr[j].y = rr[j].z = rr[j].w = -1;
    }
  }
  __syncthreads();

  if (t < 32){
    int cme = lcnt[t];
    int v = cme;
    #pragma unroll
    for (int o = 1; o < 32; o <<= 1){
      int u = __shfl_up(v, o);
      if (t >= o) v += u;
    }
    int excl = v - cme;
    if (cme){
      int g = atomicAdd(&c1cur[t*16], cme);
      lbase[t] = t*CAP1 + g - excl;
    }
    lcnt[t] = excl;                  // becomes local cursor
  }
  __syncthreads();

  #pragma unroll
  for (int j = 0; j < 4; ++j){
    int li4 = t + j*256;
    if (li4 < nv){
      int4   cc = cv[li4];
      float4 vf = fv[li4];
      int   rs[4] = {rr[j].x, rr[j].y, rr[j].z, rr[j].w};
      int   cs[4] = {cc.x, cc.y, cc.z, cc.w};
      float vs[4] = {vf.x, vf.y, vf.z, vf.w};
      #pragma unroll
      for (int c = 0; c < 4; ++c){
        int b  = rs[c] >> 12;
        int pos = atomicAdd(&lcnt[b], 1);
        int dest = lbase[b] + pos;
        if (dest < b*CAP1 + CAP1){
          stage[pos] = make_int2(((rs[c] & 4095) << 17) | cs[c], __float_as_int(vs[c]));
          sdst[pos]  = lbase[b];
        } else {
          sdst[pos] = SENTINEL;
          int o = atomicAdd(ovf_cnt, 1);
          if (o < OVF_CAP) ovf[o] = make_int4(rs[c], cs[c], __float_as_int(vs[c]), 0);
        }
      }
    }
  }
  __syncthreads();

  for (int j = t; j < cnt; j += 256){
    int d = sdst[j];
    if (d != SENTINEL) ebkt1[d + j] = stage[j];
  }
}

// ---------------------------------------------------------------------------
// K2 = mlp (blocks [0,1563)) || scat2 (blocks [1563, 1563+1650)).
// Shared memory is a 25 KB union. mlp and scat2 are data-independent; the
// fusion rides scat2's 51 MB of traffic under mlp's BW-bound 205 MB X read.
// mlp now uses hardware bf16 converts (f2bfh) instead of 4-op manual RNE.
// ---------------------------------------------------------------------------
__global__ __launch_bounds__(256) void k2(
    const float* __restrict__ X, const float* __restrict__ b1,
    const float* __restrict__ b2,
    const unsigned short* __restrict__ w1f, const unsigned short* __restrict__ w2f,
    unsigned short* __restrict__ logits,
    const int* __restrict__ c1cur, const int2* __restrict__ ebkt1,
    int* __restrict__ bcur, int* __restrict__ ovf_cnt, int4* __restrict__ ovf,
    int2* __restrict__ ebkt){
  __shared__ __align__(16) char smem[25088];
  int tid = threadIdx.x;

  if (blockIdx.x < MLP_BLKS){
    // ---------------- MLP: logits(bf16) = relu(X@W1+b1)@W2+b2 --------------
    float (*lds)[16][68] = (float (*)[16][68])smem;
    int wid  = tid >> 6, lane = tid & 63;
    int m    = lane & 15, q = lane >> 4;
    int base = blockIdx.x * 64 + wid * 16;
    if (base > N_NODES - 16) base = N_NODES - 16;   // tail waves redo last tile (benign)

    const float* rp = X + (size_t)(base + m) * F_IN + q * 8;
    const v8s* w1v = (const v8s*)w1f;
    const v8s* w2v = (const v8s*)w2f;

    v4f a0c = {0,0,0,0}, a1c = {0,0,0,0}, a2c = {0,0,0,0}, a3c = {0,0,0,0};
    #pragma unroll
    for (int ks = 0; ks < 16; ++ks){
      const float4* pa = (const float4*)(rp + ks * 32);
      float4 x0 = pa[0], x1 = pa[1];
      v8s af;
      af[0]=f2bfh(x0.x); af[1]=f2bfh(x0.y); af[2]=f2bfh(x0.z); af[3]=f2bfh(x0.w);
      af[4]=f2bfh(x1.x); af[5]=f2bfh(x1.y); af[6]=f2bfh(x1.z); af[7]=f2bfh(x1.w);
      a0c = __builtin_amdgcn_mfma_f32_16x16x32_bf16(af, w1v[(ks*4+0)*64 + lane], a0c, 0,0,0);
      a1c = __builtin_amdgcn_mfma_f32_16x16x32_bf16(af, w1v[(ks*4+1)*64 + lane], a1c, 0,0,0);
      a2c = __builtin_amdgcn_mfma_f32_16x16x32_bf16(af, w1v[(ks*4+2)*64 + lane], a2c, 0,0,0);
      a3c = __builtin_amdgcn_mfma_f32_16x16x32_bf16(af, w1v[(ks*4+3)*64 + lane], a3c, 0,0,0);
    }

    float b1v0 = b1[m], b1v1 = b1[16+m], b1v2 = b1[32+m], b1v3 = b1[48+m];
    #pragma unroll
    for (int r = 0; r < 4; ++r){
      int row = q*4 + r;
      lds[wid][row][     m] = fmaxf(a0c[r] + b1v0, 0.f);
      lds[wid][row][16 + m] = fmaxf(a1c[r] + b1v1, 0.f);
      lds[wid][row][32 + m] = fmaxf(a2c[r] + b1v2, 0.f);
      lds[wid][row][48 + m] = fmaxf(a3c[r] + b1v3, 0.f);
    }
    __syncthreads();

    v4f c0 = {0,0,0,0}, c1 = {0,0,0,0}, c2 = {0,0,0,0}, c3 = {0,0,0,0};
    #pragma unroll
    for (int k2i = 0; k2i < 2; ++k2i){
      const float4* ph = (const float4*)&lds[wid][m][k2i*32 + q*8];
      float4 h0 = ph[0], h1 = ph[1];
      v8s af;
      af[0]=f2bfh(h0.x); af[1]=f2bfh(h0.y); af[2]=f2bfh(h0.z); af[3]=f2bfh(h0.w);
      af[4]=f2bfh(h1.x); af[5]=f2bfh(h1.y); af[6]=f2bfh(h1.z); af[7]=f2bfh(h1.w);
      c0 = __builtin_amdgcn_mfma_f32_16x16x32_bf16(af, w2v[(k2i*4+0)*64 + lane], c0, 0,0,0);
      c1 = __builtin_amdgcn_mfma_f32_16x16x32_bf16(af, w2v[(k2i*4+1)*64 + lane], c1, 0,0,0);
      c2 = __builtin_amdgcn_mfma_f32_16x16x32_bf16(af, w2v[(k2i*4+2)*64 + lane], c2, 0,0,0);
      c3 = __builtin_amdgcn_mfma_f32_16x16x32_bf16(af, w2v[(k2i*4+3)*64 + lane], c3, 0,0,0);
    }

    float b2v0 = b2[m], b2v1 = b2[16+m], b2v2 = b2[32+m], b2v3 = b2[48+m];
    unsigned short* lp = logits + (size_t)base * NCLS;
    #pragma unroll
    for (int r = 0; r < 4; ++r){
      int row = q*4 + r;
      lp[row*NCLS +      m] = (unsigned short)f2bfh(c0[r] + b2v0);
      lp[row*NCLS + 16 + m] = (unsigned short)f2bfh(c1[r] + b2v1);
      lp[row*NCLS + 32 + m] = (unsigned short)f2bfh(c2[r] + b2v2);
      lp[row*NCLS + 48 + m] = (unsigned short)f2bfh(c3[r] + b2v3);
    }
    return;
  }

  // ------------- scat2: coarse region chunk -> 64 nested fine buckets ------
  int2* stage = (int2*)smem;               // 16384 B
  int*  sdst  = (int*)(smem + 16384);      //  8192 B
  int*  lcnt  = (int*)(smem + 24576);      //   256 B
  int*  lbase = (int*)(smem + 24832);      //   256 B
  int sbid = blockIdx.x - MLP_BLKS;
  int c  = sbid / C2BLKS;
  int k0 = sbid % C2BLKS;

  int cntc = c1cur[c*16];
  if (cntc > CAP1) cntc = CAP1;
  int start = k0 * CHUNK2;
  if (start >= cntc) return;                 // uniform across block
  int cnt = min(CHUNK2, cntc - start);
  const int2* src = ebkt1 + (size_t)c * CAP1 + start;

  if (tid < 64) lcnt[tid] = 0;
  __syncthreads();

  int2 ev[8];
  #pragma unroll
  for (int k = 0; k < 8; ++k){
    int li = tid + k*256;
    if (li < cnt){
      ev[k] = src[li];
      atomicAdd(&lcnt[(((unsigned)ev[k].x) >> 17) >> 6], 1);
    } else ev[k].x = -1;
  }
  __syncthreads();

  if (tid < 64){
    int cme = lcnt[tid];
    int v = cme;
    #pragma unroll
    for (int o = 1; o < 64; o <<= 1){
      int u = __shfl_up(v, o);
      if (tid >= o) v += u;
    }
    int excl = v - cme;
    if (cme){
      int gb = c*64 + tid;                   // global fine bucket
      int g = atomicAdd(&bcur[gb*16], cme);
      lbase[tid] = gb*CAP + g - excl;
    }
    lcnt[tid] = excl;
  }
  __syncthreads();

  #pragma unroll
  for (int k = 0; k < 8; ++k){
    if (ev[k].x >= 0){
      unsigned x = (unsigned)ev[k].x;
      int lr12 = (int)(x >> 17);
      int fb   = lr12 >> 6;
      int pos = atomicAdd(&lcnt[fb], 1);
      int dest = lbase[fb] + pos;
      if (dest < (c*64 + fb)*CAP + CAP){
        stage[pos] = make_int2(((lr12 & 63) << 17) | (int)(x & 0x1FFFFu), ev[k].y);
        sdst[pos]  = lbase[fb];
      } else {
        sdst[pos] = SENTINEL;
        int o = atomicAdd(ovf_cnt, 1);
        if (o < OVF_CAP) ovf[o] = make_int4(c*4096 + lr12, (int)(x & 0x1FFFFu), ev[k].y, 0);
      }
    }
  }
  __syncthreads();

  for (int j = tid; j < cnt; j += 256){
    int d = sdst[j];
    if (d != SENTINEL) ebkt[d + j] = stage[j];
  }
}

// ---------------------------------------------------------------------------
// K3: fused counting-sort + aggregate. Single global read of ebkt: each
// thread stages its <=10 edges in registers (static unroll -> stays in
// VGPRs), counts from regs, scans, ds-writes sorted from regs. Then the
// proven quarter-wave-per-edge register accumulate + shfl reduce + float4
// store, with the (empty) overflow fix-up folded in.
// ---------------------------------------------------------------------------
__global__ __launch_bounds__(256) void bucket_agg(
    const int* __restrict__ bcur, const int2* __restrict__ ebkt,
    const unsigned short* __restrict__ logits, float* __restrict__ out,
    const int* __restrict__ ovf_cnt, const int4* __restrict__ ovfl){
  __shared__ int2 sorted[CAP];        // 19456 B
  __shared__ int  rc[BROWS];
  __shared__ int  rbase[BROWS + 1];
  __shared__ int  rcur[BROWS];
  int b = blockIdx.x, t = threadIdx.x;
  int w = t >> 6, lane = t & 63;
  int h = lane & 15, sel = lane >> 4;

  if (t < BROWS) rc[t] = 0;
  __syncthreads();

  int cnt = bcur[b * 16];
  if (cnt > CAP) cnt = CAP;
  const int2* ep = ebkt + (size_t)b * CAP;
  int ocnt = ovf_cnt[0];
  if (ocnt > OVF_CAP) ocnt = OVF_CAP;

  // single pass: load to regs + count (CAP/256 = 9.5 -> 10 static slots)
  int2 ev[10];
  #pragma unroll
  for (int k = 0; k < 10; ++k){
    int j = t + k*256;
    if (j < cnt){
      ev[k] = ep[j];
      atomicAdd(&rc[((unsigned)ev[k].x) >> 17], 1);
    } else ev[k].x = -1;
  }
  __syncthreads();

  if (t < BROWS){
    int c = rc[t];
    int v = c;
    #pragma unroll
    for (int o = 1; o < 64; o <<= 1){
      int u = __shfl_up(v, o);
      if (lane >= o) v += u;
    }
    rbase[t + 1] = v;
    rcur[t]      = v - c;
    if (t == 0) rbase[0] = 0;
  }
  __syncthreads();

  #pragma unroll
  for (int k = 0; k < 10; ++k){
    if (ev[k].x >= 0){
      int pos = atomicAdd(&rcur[((unsigned)ev[k].x) >> 17], 1);
      sorted[pos] = ev[k];
    }
  }
  __syncthreads();

  const uint2* lg = (const uint2*)logits;
  int row0 = b * BROWS;
  for (int n = w; n < BROWS; n += 4){
    int node = row0 + n;
    if (node >= N_NODES) break;
    int s = rbase[n], e = rbase[n + 1];
    float a0 = 0.f, a1 = 0.f, a2 = 0.f, a3 = 0.f;
    int i = s;
    for (; i + 16 <= e; i += 16){
      int2 e0 = sorted[i      + sel];
      int2 e1 = sorted[i + 4  + sel];
      int2 e2 = sorted[i + 8  + sel];
      int2 e3 = sorted[i + 12 + sel];
      uint2 u0 = lg[((size_t)(e0.x & 0x1FFFF) << 4) + h];
      uint2 u1 = lg[((size_t)(e1.x & 0x1FFFF) << 4) + h];
      uint2 u2 = lg[((size_t)(e2.x & 0x1FFFF) << 4) + h];
      uint2 u3 = lg[((size_t)(e3.x & 0x1FFFF) << 4) + h];
      float v0 = __int_as_float(e0.y), v1 = __int_as_float(e1.y);
      float v2 = __int_as_float(e2.y), v3 = __int_as_float(e3.y);
      a0 = fmaf(v0, bflo(u0.x), a0); a1 = fmaf(v0, bfhi(u0.x), a1);
      a2 = fmaf(v0, bflo(u0.y), a2); a3 = fmaf(v0, bfhi(u0.y), a3);
      a0 = fmaf(v1, bflo(u1.x), a0); a1 = fmaf(v1, bfhi(u1.x), a1);
      a2 = fmaf(v1, bflo(u1.y), a2); a3 = fmaf(v1, bfhi(u1.y), a3);
      a0 = fmaf(v2, bflo(u2.x), a0); a1 = fmaf(v2, bfhi(u2.x), a1);
      a2 = fmaf(v2, bflo(u2.y), a2); a3 = fmaf(v2, bfhi(u2.y), a3);
      a0 = fmaf(v3, bflo(u3.x), a0); a1 = fmaf(v3, bfhi(u3.x), a1);
      a2 = fmaf(v3, bflo(u3.y), a2); a3 = fmaf(v3, bfhi(u3.y), a3);
    }
    for (; i < e; i += 4){
      int idx = i + sel;
      int col = 0; float v = 0.f;
      if (idx < e){ int2 evv = sorted[idx]; col = evv.x & 0x1FFFF; v = __int_as_float(evv.y); }
      uint2 u = lg[((size_t)col << 4) + h];
      a0 = fmaf(v, bflo(u.x), a0); a1 = fmaf(v, bfhi(u.x), a1);
      a2 = fmaf(v, bflo(u.y), a2); a3 = fmaf(v, bfhi(u.y), a3);
    }
    a0 += __shfl_xor(a0, 16); a0 += __shfl_xor(a0, 32);
    a1 += __shfl_xor(a1, 16); a1 += __shfl_xor(a1, 32);
    a2 += __shfl_xor(a2, 16); a2 += __shfl_xor(a2, 32);
    a3 += __shfl_xor(a3, 16); a3 += __shfl_xor(a3, 32);
    if (sel == 0){
      if (ocnt){                       // overflow fix-up (empty in practice)
        for (int j = 0; j < ocnt; ++j){
          int4 eo = ovfl[j];
          if (eo.x == node){
            uint2 u = lg[((size_t)eo.y << 4) + h];
            float v = __int_as_float(eo.z);
            a0 = fmaf(v, bflo(u.x), a0); a1 = fmaf(v, bfhi(u.x), a1);
            a2 = fmaf(v, bflo(u.y), a2); a3 = fmaf(v, bfhi(u.y), a3);
          }
        }
      }
      float4* op = (float4*)(out + (size_t)node * NCLS);
      op[h] = make_float4(a0, a1, a2, a3);
    }
  }
}

// Fallback if workspace is too small: direct atomic scatter.
__global__ void scatter_atomic(const int* __restrict__ rows, const int* __restrict__ cols,
                               const float* __restrict__ vals,
                               const unsigned short* __restrict__ logits,
                               float* __restrict__ out){
  long g = (long)blockIdx.x * 256 + threadIdx.x;
  int e = (int)(g >> 6), c = (int)(g & 63);
  if (e < N_EDGES){
    float lv = __uint_as_float(((unsigned)logits[(size_t)cols[e] * NCLS + c]) << 16);
    atomicAdd(&out[(size_t)rows[e] * NCLS + c], vals[e] * lv);
  }
}

extern "C" void kernel_launch(void* const* d_in, const int* in_sizes, int n_in,
                              void* d_out, int out_size, void* d_ws, size_t ws_size,
                              hipStream_t stream){
  const float* X     = (const float*)d_in[0];
  const int*   erows = (const int*)  d_in[1];
  const int*   ecols = (const int*)  d_in[2];
  const float* evals = (const float*)d_in[3];
  const float* W1    = (const float*)d_in[4];
  const float* b1    = (const float*)d_in[5];
  const float* W2    = (const float*)d_in[6];
  const float* b2    = (const float*)d_in[7];
  float* out = (float*)d_out;

  char* ws = (char*)d_ws;
  size_t off = 0;
  auto alloc = [&](size_t bytes) -> char* {
    char* p = ws + off;
    off = (off + bytes + 255) & ~(size_t)255;
    return p;
  };
  unsigned short* logits = (unsigned short*)alloc((size_t)N_NODES * NCLS * 2); // 12.8 MB
  unsigned short* w1f    = (unsigned short*)alloc(16*4*64*8 * 2);
  unsigned short* w2f    = (unsigned short*)alloc(2*4*64*8 * 2);
  int*  bcur  = (int*)alloc((size_t)NZERO * 4);   // fine cursors | coarse cursors | ovf_cnt
  int*  c1cur = bcur + NBKT*16;
  int*  ovfc  = bcur + NBKT*16 + NCOARSE*16;
  int4* ovf   = (int4*)alloc((size_t)OVF_CAP * 16);
  int2* ebkt1 = (int2*)alloc((size_t)NCOARSE * CAP1 * 8);  // 27.0 MB coarse regions
  int2* ebkt  = (int2*)alloc((size_t)NBKT * CAP * 8);      // 30.4 MB fine regions
  size_t full_need = off;   // ~71 MB

  if (ws_size >= full_need){
    hipMemsetAsync(bcur, 0, (size_t)NZERO * 4, stream);    // ~100 KB, ~2 us
    k1<<<PREP_BLKS + SC1_BLKS, 256, 0, stream>>>(
        erows, ecols, evals, c1cur, ovfc, ovf, ebkt1, W1, W2, w1f, w2f);
    k2<<<MLP_BLKS + SC2_BLKS, 256, 0, stream>>>(
        X, b1, b2, w1f, w2f, logits, c1cur, ebkt1, bcur, ovfc, ovf, ebkt);
    bucket_agg<<<NBKT, 256, 0, stream>>>(bcur, ebkt, logits, out, ovfc, ovf);
  } else {
    // prep-only grid (prep blocks are [0, PREP_BLKS)), then mlp-only grid
    k1<<<PREP_BLKS, 256, 0, stream>>>(
        erows, ecols, evals, c1cur, ovfc, ovf, ebkt1, W1, W2, w1f, w2f);
    k2<<<MLP_BLKS, 256, 0, stream>>>(
        X, b1, b2, w1f, w2f, logits, c1cur, ebkt1, bcur, ovfc, ovf, ebkt);
    hipMemsetAsync(out, 0, (size_t)N_NODES * NCLS * 4, stream);
    scatter_atomic<<<(int)(((long)N_EDGES * 64 + 255) / 256), 256, 0, stream>>>(
        erows, ecols, evals, logits, out);
  }
}